// Round 15
// baseline (141.950 us; speedup 1.0000x reference)
//
#include <hip/hip_runtime.h>
#include <math.h>

#define B_  8
#define C_  384
#define NS_ 1024
#define HEADS_ 12
#define HD_ 32
#define GROUPS_ 3
#define CG_ 128
#define EPS_ 1e-5f
// 1/sqrt(32) * log2(e)  (exp computed as exp2)
#define QSC2 (0.17677669529663687f * 1.4426950408889634f)

typedef __attribute__((ext_vector_type(8))) short bf16x8;
typedef __attribute__((ext_vector_type(4))) short bf16x4;
typedef __attribute__((ext_vector_type(4))) float f32x4;
typedef __attribute__((ext_vector_type(8))) __bf16 b8;

static __device__ __forceinline__ short f2b(float f) {
  union { float f; unsigned u; } v; v.f = f;
  unsigned r = v.u + 0x7fffu + ((v.u >> 16) & 1u);   // RNE
  return (short)(r >> 16);
}
static __device__ __forceinline__ float b2f(short s) {
  union { unsigned u; float f; } v; v.u = ((unsigned)(unsigned short)s) << 16;
  return v.f;
}

#if __has_builtin(__builtin_amdgcn_exp2f)
#define EXP2(x) __builtin_amdgcn_exp2f(x)
#else
#define EXP2(x) exp2f(x)
#endif

static __device__ __forceinline__ unsigned cvtpk(float lo, float hi) {
  unsigned r;
  asm("v_cvt_pk_bf16_f32 %0, %1, %2" : "=v"(r) : "v"(lo), "v"(hi));
  return r;
}

static __device__ __forceinline__ f32x4 MFMA(bf16x8 a, bf16x8 b, f32x4 c) {
  return __builtin_amdgcn_mfma_f32_16x16x32_bf16(
      __builtin_bit_cast(b8, a), __builtin_bit_cast(b8, b), c, 0, 0, 0);
}

// ---------------------------------------------------------------------------
// prep mega-kernel (round-13 proven)
// ---------------------------------------------------------------------------
__global__ __launch_bounds__(256) void prep(
    const float* __restrict__ x1, const float* __restrict__ x2,
    const float* __restrict__ Wq, const float* __restrict__ Wk,
    const float* __restrict__ Wv, const float* __restrict__ Wo,
    const float* __restrict__ dw,
    short* __restrict__ x1t, short* __restrict__ x2t,
    short* __restrict__ Wqb, short* __restrict__ Wkb,
    short* __restrict__ Wvb, short* __restrict__ Wob,
    float* __restrict__ dwp) {
  __shared__ float tl[32][33];
  int id = blockIdx.x;
  int tid = threadIdx.x;
  int tx = tid & 31, ty = tid >> 5;
  if (id < 3072) {                       // x1 (8,384,1024) -> (8,1024,384) bf16
    int nb = id & 31, cb = (id >> 5) % 12, b = id / 384;
    int n0 = nb * 32, c0 = cb * 32;
#pragma unroll
    for (int i = 0; i < 4; ++i)
      tl[ty + 8 * i][tx] = x1[((size_t)b * C_ + c0 + ty + 8 * i) * NS_ + n0 + tx];
    __syncthreads();
#pragma unroll
    for (int i = 0; i < 4; ++i)
      x1t[((size_t)b * NS_ + n0 + ty + 8 * i) * C_ + c0 + tx] = f2b(tl[tx][ty + 8 * i]);
  } else if (id < 6144) {                // x2 (24,128,1024) -> (24,1024,128) bf16
    int i = id - 3072;
    int nb = i & 31, cb = (i >> 5) & 3, bg = i / 128;
    int n0 = nb * 32, c0 = cb * 32;
#pragma unroll
    for (int j = 0; j < 4; ++j)
      tl[ty + 8 * j][tx] = x2[((size_t)bg * CG_ + c0 + ty + 8 * j) * NS_ + n0 + tx];
    __syncthreads();
#pragma unroll
    for (int j = 0; j < 4; ++j)
      x2t[((size_t)bg * NS_ + n0 + ty + 8 * j) * CG_ + c0 + tx] = f2b(tl[tx][ty + 8 * j]);
  } else if (id < 8448) {                // weights fp32 -> bf16 (4 x 576 blocks)
    int i = id - 6144;
    int mat = i / 576;
    int e = (i % 576) * 256 + tid;
    const float* s = mat == 0 ? Wq : mat == 1 ? Wk : mat == 2 ? Wv : Wo;
    short*       d = mat == 0 ? Wqb : mat == 1 ? Wkb : mat == 2 ? Wvb : Wob;
    d[e] = f2b(s[e]);
  } else {                               // dw (128,25) -> dwp (25,128)
    int e = (id - 8448) * 256 + tid;
    if (e < 25 * CG_) { int t = e / CG_, c = e % CG_; dwp[e] = dw[c * 25 + t]; }
  }
}

// ---------------------------------------------------------------------------
// K-loop helpers
// ---------------------------------------------------------------------------
#define GLOADA(kc_, AF)                                                        \
  _Pragma("unroll")                                                            \
  for (int rt = 0; rt < 4; ++rt)                                               \
    AF[rt] = *(const bf16x8*)(Ab + (size_t)(n0 + wr + rt * 16 + r15) * C_ +    \
                              (kc_) + g * 8);
#define GLOADB(kc_, BF, WP, MOFF)                                              \
  _Pragma("unroll")                                                            \
  for (int ct = 0; ct < 4; ++ct)                                               \
    BF[ct] = *(const bf16x8*)((WP) + (size_t)((MOFF) + ct * 16 + r15) * C_ +   \
                              (kc_) + g * 8);
#define GMFMA(AF, BF)                                                          \
  _Pragma("unroll")                                                            \
  for (int rt = 0; rt < 4; ++rt)                                               \
    _Pragma("unroll")                                                          \
    for (int ct = 0; ct < 4; ++ct) acc[rt][ct] = MFMA(AF[rt], BF[ct], acc[rt][ct]);

// ---------------------------------------------------------------------------
// Q-projection GEMM (round-13 proven MODE 1)
// ---------------------------------------------------------------------------
__global__ __launch_bounds__(256) void gemm_q(
    const short* __restrict__ A, const short* __restrict__ Wb,
    const float* __restrict__ bias, short* __restrict__ outb,
    float* __restrict__ outf) {
  int b = blockIdx.z;
  int n0 = blockIdx.x * 128;
  int m0 = blockIdx.y * 128;
  int wv = threadIdx.x >> 6;
  int lane = threadIdx.x & 63;
  int g = lane >> 4, r15 = lane & 15;
  int wr = (wv >> 1) * 64, wc = (wv & 1) * 64;

  const short* Ab = A + (size_t)b * NS_ * C_;
  f32x4 acc[4][4];
#pragma unroll
  for (int i = 0; i < 4; ++i)
#pragma unroll
    for (int j = 0; j < 4; ++j) acc[i][j] = (f32x4){0.f, 0.f, 0.f, 0.f};

  bf16x8 afA[4], bfA[4], afB[4], bfB[4];
  GLOADA(0, afA); GLOADB(0, bfA, Wb, m0 + wc);
#pragma unroll
  for (int cp = 0; cp < 6; ++cp) {
    GLOADA(64 * cp + 32, afB); GLOADB(64 * cp + 32, bfB, Wb, m0 + wc);
    GMFMA(afA, bfA);
    if (cp < 5) { GLOADA(64 * cp + 64, afA); GLOADB(64 * cp + 64, bfA, Wb, m0 + wc); }
    GMFMA(afB, bfB);
  }

#pragma unroll
  for (int rt = 0; rt < 4; ++rt)
#pragma unroll
    for (int ct = 0; ct < 4; ++ct) {
      int m = m0 + wc + ct * 16 + r15;
      int nb = n0 + wr + rt * 16 + g * 4;
      float bv = bias[m];
      f32x4 v = acc[rt][ct];
      v.x += bv; v.y += bv; v.z += bv; v.w += bv;
      *(f32x4*)(outf + ((size_t)b * C_ + m) * NS_ + nb) = v;
      outb[((size_t)b * NS_ + nb + 0) * C_ + m] = f2b(v.x * QSC2);
      outb[((size_t)b * NS_ + nb + 1) * C_ + m] = f2b(v.y * QSC2);
      outb[((size_t)b * NS_ + nb + 2) * C_ + m] = f2b(v.z * QSC2);
      outb[((size_t)b * NS_ + nb + 3) * C_ + m] = f2b(v.w * QSC2);
    }
}

// ---------------------------------------------------------------------------
// Output GEMM with inline attention-merge on the A-load path (round-14 proven):
// A[n][c] = (op0[n][c] + op1[n][c]) / (l0[h(c)][n] + l1[h(c)][n])
// out = A @ Wo^T + bo + x1 (d-major f32).
// ---------------------------------------------------------------------------
#define GLOADAM(kc_, AF)                                                       \
  _Pragma("unroll")                                                            \
  for (int rt = 0; rt < 4; ++rt) {                                             \
    int n_ = n0 + wr + rt * 16 + r15;                                          \
    size_t off_ = ((size_t)bz * NS_ + n_) * C_ + (kc_) + g * 8;                \
    bf16x8 a0_ = *(const bf16x8*)(op0 + off_);                                 \
    bf16x8 a1_ = *(const bf16x8*)(op1 + off_);                                 \
    int h_ = (kc_) >> 5;                                                       \
    float l_ = lp[((size_t)(bz * HEADS_) + h_) * NS_ + n_] +                   \
               lp[((size_t)((B_ + bz) * HEADS_) + h_) * NS_ + n_];             \
    float rl_ = 1.f / l_;                                                      \
    union { unsigned u[4]; bf16x8 v; } r_;                                     \
    _Pragma("unroll")                                                          \
    for (int j2 = 0; j2 < 4; ++j2)                                             \
      r_.u[j2] = cvtpk((b2f(a0_[2 * j2]) + b2f(a1_[2 * j2])) * rl_,            \
                       (b2f(a0_[2 * j2 + 1]) + b2f(a1_[2 * j2 + 1])) * rl_);   \
    AF[rt] = r_.v;                                                             \
  }

__global__ __launch_bounds__(256) void gemm_of(
    const short* __restrict__ op0, const short* __restrict__ op1,
    const float* __restrict__ lp, const short* __restrict__ Wb,
    const float* __restrict__ bias, const float* __restrict__ res,
    float* __restrict__ outf) {
  int bz = blockIdx.z;
  int n0 = blockIdx.x * 128;
  int m0 = blockIdx.y * 128;
  int wv = threadIdx.x >> 6;
  int lane = threadIdx.x & 63;
  int g = lane >> 4, r15 = lane & 15;
  int wr = (wv >> 1) * 64, wc = (wv & 1) * 64;

  f32x4 acc[4][4];
#pragma unroll
  for (int i = 0; i < 4; ++i)
#pragma unroll
    for (int j = 0; j < 4; ++j) acc[i][j] = (f32x4){0.f, 0.f, 0.f, 0.f};

  bf16x8 afA[4], bfA[4], afB[4], bfB[4];
  GLOADAM(0, afA); GLOADB(0, bfA, Wb, m0 + wc);
#pragma unroll
  for (int cp = 0; cp < 6; ++cp) {
    GLOADAM(64 * cp + 32, afB); GLOADB(64 * cp + 32, bfB, Wb, m0 + wc);
    GMFMA(afA, bfA);
    if (cp < 5) { GLOADAM(64 * cp + 64, afA); GLOADB(64 * cp + 64, bfA, Wb, m0 + wc); }
    GMFMA(afB, bfB);
  }

#pragma unroll
  for (int rt = 0; rt < 4; ++rt)
#pragma unroll
    for (int ct = 0; ct < 4; ++ct) {
      int m = m0 + wc + ct * 16 + r15;
      int nb = n0 + wr + rt * 16 + g * 4;
      float bv = bias[m];
      f32x4 v = acc[rt][ct];
      const f32x4 rv = *(const f32x4*)(res + ((size_t)bz * C_ + m) * NS_ + nb);
      v.x += bv + rv.x; v.y += bv + rv.y; v.z += bv + rv.z; v.w += bv + rv.w;
      *(f32x4*)(outf + ((size_t)bz * C_ + m) * NS_ + nb) = v;
    }
}

// ---------------------------------------------------------------------------
// Fused K+V projection GEMM (round-13 proven).
// ---------------------------------------------------------------------------
__global__ __launch_bounds__(256) void gemm_kv(
    const short* __restrict__ A, const short* __restrict__ Wkb,
    const short* __restrict__ Wvb, const float* __restrict__ bkv,
    const float* __restrict__ bvv, short* __restrict__ kblk,
    short* __restrict__ vblk) {
  int b = blockIdx.z;
  int n0 = blockIdx.x * 128;
  int m0 = blockIdx.y * 64;
  int wv = threadIdx.x >> 6;
  int lane = threadIdx.x & 63;
  int g = lane >> 4, r15 = lane & 15;
  int wr = (wv >> 1) * 64;
  int isv = wv & 1;
  const short* Wsel = isv ? Wvb : Wkb;
  const float* bsel = isv ? bvv : bkv;

  const short* Ab = A + (size_t)b * NS_ * C_;
  f32x4 acc[4][4];
#pragma unroll
  for (int i = 0; i < 4; ++i)
#pragma unroll
    for (int j = 0; j < 4; ++j) acc[i][j] = (f32x4){0.f, 0.f, 0.f, 0.f};

  bf16x8 afA[4], bfA[4], afB[4], bfB[4];
  GLOADA(0, afA); GLOADB(0, bfA, Wsel, m0);
#pragma unroll
  for (int cp = 0; cp < 6; ++cp) {
    GLOADA(64 * cp + 32, afB); GLOADB(64 * cp + 32, bfB, Wsel, m0);
    GMFMA(afA, bfA);
    if (cp < 5) { GLOADA(64 * cp + 64, afA); GLOADB(64 * cp + 64, bfA, Wsel, m0); }
    GMFMA(afB, bfB);
  }

#pragma unroll
  for (int rt = 0; rt < 4; ++rt)
#pragma unroll
    for (int ct = 0; ct < 4; ++ct) {
      int m = m0 + ct * 16 + r15;
      int nb = n0 + wr + rt * 16 + g * 4;
      float bv = bsel[m];
      f32x4 v = acc[rt][ct];
      v.x += bv; v.y += bv; v.z += bv; v.w += bv;
      int h = m >> 5, dh = m & 31;
      if (!isv) {
        size_t hb = ((size_t)(b * HEADS_ + h) * 32 + (nb >> 5)) * 1024 +
                    (((nb >> 4) & 1) ? 512 : 0);
        int base_l = (nb & 15) | ((dh >> 3) << 4);
        int jj = dh & 7;
        kblk[hb + (size_t)(base_l + 0) * 8 + jj] = f2b(v.x);
        kblk[hb + (size_t)(base_l + 1) * 8 + jj] = f2b(v.y);
        kblk[hb + (size_t)(base_l + 2) * 8 + jj] = f2b(v.z);
        kblk[hb + (size_t)(base_l + 3) * 8 + jj] = f2b(v.w);
      } else {
        int dt = dh >> 4, q15v = dh & 15;
        int kk = nb & 31;
        int half = kk >> 4, gk = (kk & 15) >> 2;
        size_t off = ((size_t)(b * HEADS_ + h) * 32 + (nb >> 5)) * 1024 +
                     dt * 512 + (size_t)((q15v | (gk << 4))) * 8 + half * 4;
        bf16x4 s4 = {f2b(v.x), f2b(v.y), f2b(v.z), f2b(v.w)};
        *(bf16x4*)(vblk + off) = s4;
      }
    }
}

// ---------------------------------------------------------------------------
// offsample4 (round-13 proven)
// ---------------------------------------------------------------------------
__global__ __launch_bounds__(256) void offsample4(
    const float* __restrict__ qd, const short* __restrict__ x2t,
    const float* __restrict__ dwp, const float* __restrict__ dwb,
    const float* __restrict__ lng, const float* __restrict__ lnb,
    const float* __restrict__ offw, short* __restrict__ samp) {
  int bg = blockIdx.x, y = blockIdx.y;
  int tid = threadIdx.x;
  int xg = tid >> 5, cc = tid & 31;
  int x0 = xg << 2, c0 = cc << 2;

  const float* qb = qd + ((size_t)bg * CG_ + c0) * NS_;

  f32x4 dwb4 = *(const f32x4*)(dwb + c0);
  float a[4][4];
#pragma unroll
  for (int i = 0; i < 4; ++i)
#pragma unroll
    for (int p = 0; p < 4; ++p) a[i][p] = dwb4[i];

#pragma unroll
  for (int dy = -2; dy <= 2; ++dy) {
    int yy = y + dy;
    if (yy < 0 || yy > 31) continue;
    f32x4 w0 = *(const f32x4*)(dwp + ((dy + 2) * 5 + 0) * CG_ + c0);
    f32x4 w1 = *(const f32x4*)(dwp + ((dy + 2) * 5 + 1) * CG_ + c0);
    f32x4 w2 = *(const f32x4*)(dwp + ((dy + 2) * 5 + 2) * CG_ + c0);
    f32x4 w3 = *(const f32x4*)(dwp + ((dy + 2) * 5 + 3) * CG_ + c0);
    f32x4 w4 = *(const f32x4*)(dwp + ((dy + 2) * 5 + 4) * CG_ + c0);
#pragma unroll
    for (int i = 0; i < 4; ++i) {
      const float* row = qb + (size_t)i * NS_ + yy * 32;
      f32x4 wa = (f32x4){0.f, 0.f, 0.f, 0.f};
      f32x4 wcv = (f32x4){0.f, 0.f, 0.f, 0.f};
      if (x0 >= 4)  wa  = *(const f32x4*)(row + x0 - 4);
      f32x4 wb = *(const f32x4*)(row + x0);
      if (x0 <= 24) wcv = *(const f32x4*)(row + x0 + 4);
      float w[12] = {wa[0], wa[1], wa[2], wa[3], wb[0], wb[1], wb[2], wb[3],
                     wcv[0], wcv[1], wcv[2], wcv[3]};
      float wt[5] = {w0[i], w1[i], w2[i], w3[i], w4[i]};
#pragma unroll
      for (int p = 0; p < 4; ++p)
#pragma unroll
        for (int j = 0; j < 5; ++j)
          a[i][p] = fmaf(w[p + j + 2], wt[j], a[i][p]);
    }
  }

  f32x4 sum = (f32x4){0.f, 0.f, 0.f, 0.f}, sumsq = sum;
#pragma unroll
  for (int i = 0; i < 4; ++i)
#pragma unroll
    for (int p = 0; p < 4; ++p) { sum[p] += a[i][p]; sumsq[p] += a[i][p] * a[i][p]; }
#pragma unroll
  for (int m = 1; m <= 16; m <<= 1) {
#pragma unroll
    for (int p = 0; p < 4; ++p) {
      sum[p]   += __shfl_xor(sum[p], m);
      sumsq[p] += __shfl_xor(sumsq[p], m);
    }
  }
  f32x4 mu, rs;
#pragma unroll
  for (int p = 0; p < 4; ++p) {
    mu[p] = sum[p] * (1.f / CG_);
    float var = sumsq[p] * (1.f / CG_) - mu[p] * mu[p];
    rs[p] = rsqrtf(var + EPS_);
  }

  f32x4 lg = *(const f32x4*)(lng + c0);
  f32x4 lb = *(const f32x4*)(lnb + c0);
  f32x4 ow0 = *(const f32x4*)(offw + c0);
  f32x4 ow1 = *(const f32x4*)(offw + CG_ + c0);
  f32x4 o0 = (f32x4){0.f, 0.f, 0.f, 0.f}, o1 = o0;
#pragma unroll
  for (int i = 0; i < 4; ++i)
#pragma unroll
    for (int p = 0; p < 4; ++p) {
      float z = (a[i][p] - mu[p]) * rs[p] * lg[i] + lb[i];
      float u = z * fmaf(0.044715f * z, z, 1.f);
      float e = __expf(-1.5957691216057308f * u);
      float ge = z * __builtin_amdgcn_rcpf(1.f + e);
      o0[p] = fmaf(ow0[i], ge, o0[p]);
      o1[p] = fmaf(ow1[i], ge, o1[p]);
    }
#pragma unroll
  for (int m = 1; m <= 16; m <<= 1) {
#pragma unroll
    for (int p = 0; p < 4; ++p) {
      o0[p] += __shfl_xor(o0[p], m);
      o1[p] += __shfl_xor(o1[p], m);
    }
  }

  int b = bg / GROUPS_, gi = bg % GROUPS_;
  const short* xb = x2t + (size_t)bg * NS_ * CG_ + c0;
  float gy = (y + 0.5f) * 0.0625f - 1.f;
#pragma unroll
  for (int p = 0; p < 4; ++p) {
    int x = x0 + p, n = y * 32 + x;
    float gx = (x + 0.5f) * 0.0625f - 1.f;
    float px = fminf(fmaxf(o0[p] + gx, -1.f), 1.f);
    float py = fminf(fmaxf(o1[p] + gy, -1.f), 1.f);
    float ix = (px + 1.f) * 0.5f * 31.f;
    float iy = (py + 1.f) * 0.5f * 31.f;
    float x0f = floorf(ix), y0f = floorf(iy);
    float wx = ix - x0f, wy = iy - y0f;
    int xa = min(max((int)x0f, 0), 31), xbb = min(xa + 1, 31);
    int ya = min(max((int)y0f, 0), 31), yb = min(ya + 1, 31);
    int i00 = ya * 32 + xa, i01 = ya * 32 + xbb;
    int i10 = yb * 32 + xa, i11 = yb * 32 + xbb;
    float w00 = (1.f - wx) * (1.f - wy), w01 = wx * (1.f - wy);
    float w10 = (1.f - wx) * wy,         w11 = wx * wy;
    bf16x4 v00 = *(const bf16x4*)(xb + (size_t)i00 * CG_);
    bf16x4 v01 = *(const bf16x4*)(xb + (size_t)i01 * CG_);
    bf16x4 v10 = *(const bf16x4*)(xb + (size_t)i10 * CG_);
    bf16x4 v11 = *(const bf16x4*)(xb + (size_t)i11 * CG_);
    short out4[4];
#pragma unroll
    for (int j = 0; j < 4; ++j) {
      float v = w00 * b2f(v00[j]) + w01 * b2f(v01[j]) +
                w10 * b2f(v10[j]) + w11 * b2f(v11[j]);
      out4[j] = f2b(v);
    }
    *(bf16x4*)(samp + ((size_t)b * NS_ + n) * C_ + gi * CG_ + c0) = *(bf16x4*)out4;
  }
}

// ---------------------------------------------------------------------------
// Blocked-layout split-K attention (round-13 proven 2-fragment version):
// 16 chunks/wave, grid 1536, XCD-locality swizzle, 1-deep A/B prefetch.
// VGPR ~104 -> 4+ waves/SIMD. (4-fragment variant hits VGPR 236 — don't.)
// ---------------------------------------------------------------------------
__global__ __launch_bounds__(256) void attn_split(
    const short* __restrict__ qn, const short* __restrict__ kblk,
    const short* __restrict__ vblk, short* __restrict__ op0,
    short* __restrict__ op1, float* __restrict__ lp) {
  // grid 1536: L = (task%8) + 8*((task/8) + 24*qblk); task = bh*2+s
  int L = blockIdx.x;
  int tq = L >> 3;
  int task = (L & 7) + ((tq % 24) << 3);   // 0..191
  int qblk = tq / 24;                      // 0..7
  int bh = task >> 1, s = task & 1;
  int b = bh / HEADS_, h = bh % HEADS_;
  int wv = threadIdx.x >> 6, lane = threadIdx.x & 63;
  int g = lane >> 4, q15 = lane & 15;
  int q0 = qblk * 128 + wv * 32;

  const short* Qb = qn + (size_t)b * NS_ * C_ + h * HD_;
  const short* Kc = kblk + ((size_t)(b * HEADS_ + h) * 32 + s * 16) * 1024 + lane * 8;
  const short* Vc = vblk + ((size_t)(b * HEADS_ + h) * 32 + s * 16) * 1024 + lane * 8;

  bf16x8 qf[2];
  qf[0] = *(const bf16x8*)(Qb + (size_t)(q0 + q15) * C_ + g * 8);
  qf[1] = *(const bf16x8*)(Qb + (size_t)(q0 + 16 + q15) * C_ + g * 8);

  f32x4 o[2][2];
  o[0][0] = o[0][1] = o[1][0] = o[1][1] = (f32x4){0.f, 0.f, 0.f, 0.f};
  f32x4 lv[2];
  lv[0] = lv[1] = (f32x4){0.f, 0.f, 0.f, 0.f};

#define LOADC(c_, K0, K1, V0, V1)                                              \
  {                                                                            \
    K0 = *(const bf16x8*)(Kc + (c_) * 1024);                                   \
    K1 = *(const bf16x8*)(Kc + (c_) * 1024 + 512);                             \
    V0 = *(const bf16x8*)(Vc + (c_) * 1024);                                   \
    V1 = *(const bf16x8*)(Vc + (c_) * 1024 + 512);                             \
  }

#define COMPUTEC(K0, K1, V0, V1)                                               \
  {                                                                            \
    _Pragma("unroll")                                                          \
    for (int qt = 0; qt < 2; ++qt) {                                           \
      f32x4 z_ = {0.f, 0.f, 0.f, 0.f};                                         \
      f32x4 t0 = MFMA(K0, qf[qt], z_);                                         \
      f32x4 t1 = MFMA(K1, qf[qt], z_);                                         \
      f32x4 e0, e1;                                                            \
      e0.x = EXP2(t0.x); e0.y = EXP2(t0.y); e0.z = EXP2(t0.z); e0.w = EXP2(t0.w);\
      e1.x = EXP2(t1.x); e1.y = EXP2(t1.y); e1.z = EXP2(t1.z); e1.w = EXP2(t1.w);\
      lv[qt] += e0; lv[qt] += e1;                                              \
      union { unsigned u[4]; bf16x8 v; } pu;                                   \
      pu.u[0] = cvtpk(e0.x, e0.y);                                             \
      pu.u[1] = cvtpk(e0.z, e0.w);                                             \
      pu.u[2] = cvtpk(e1.x, e1.y);                                             \
      pu.u[3] = cvtpk(e1.z, e1.w);                                             \
      o[qt][0] = MFMA(V0, pu.v, o[qt][0]);                                     \
      o[qt][1] = MFMA(V1, pu.v, o[qt][1]);                                     \
    }                                                                          \
  }

  bf16x8 kA0, kA1, vA0, vA1, kB0, kB1, vB0, vB1;
  LOADC(0, kA0, kA1, vA0, vA1);
#pragma unroll
  for (int cp = 0; cp < 8; ++cp) {
    LOADC(2 * cp + 1, kB0, kB1, vB0, vB1);
    COMPUTEC(kA0, kA1, vA0, vA1);
    if (cp < 7) LOADC(2 * cp + 2, kA0, kA1, vA0, vA1);
    COMPUTEC(kB0, kB1, vB0, vB1);
  }
#undef LOADC
#undef COMPUTEC

  short* opS = s ? op1 : op0;
#pragma unroll
  for (int qt = 0; qt < 2; ++qt) {
    float lt = (lv[qt].x + lv[qt].y) + (lv[qt].z + lv[qt].w);
    lt += __shfl_xor(lt, 16);
    lt += __shfl_xor(lt, 32);
    int q = q0 + qt * 16 + q15;
    if (g == 0) lp[((size_t)(s * B_ + b) * HEADS_ + h) * NS_ + q] = lt;
#pragma unroll
    for (int dt = 0; dt < 2; ++dt) {
      f32x4 ov = o[qt][dt];
      bf16x4 s4 = {f2b(ov.x), f2b(ov.y), f2b(ov.z), f2b(ov.w)};
      *(bf16x4*)(opS + ((size_t)b * NS_ + q) * C_ + h * HD_ + dt * 16 + g * 4) = s4;
    }
  }
}

// ---------------------------------------------------------------------------
extern "C" void kernel_launch(void* const* d_in, const int* in_sizes, int n_in,
                              void* d_out, int out_size, void* d_ws, size_t ws_size,
                              hipStream_t stream) {
  const float* x1      = (const float*)d_in[0];
  const float* x2      = (const float*)d_in[1];
  const float* Wq      = (const float*)d_in[2];
  const float* bq      = (const float*)d_in[3];
  const float* Wk      = (const float*)d_in[4];
  const float* bk      = (const float*)d_in[5];
  const float* Wv      = (const float*)d_in[6];
  const float* bv      = (const float*)d_in[7];
  const float* Wo      = (const float*)d_in[8];
  const float* bo      = (const float*)d_in[9];
  const float* off_dw  = (const float*)d_in[10];
  const float* off_dwb = (const float*)d_in[11];
  const float* ln_g    = (const float*)d_in[12];
  const float* ln_b    = (const float*)d_in[13];
  const float* off_w   = (const float*)d_in[14];

  char* base = (char*)d_ws;
  const size_t SZ = (size_t)B_ * C_ * NS_;
  float* q_dC  = (float*)base;                   // f32, dead after offsample4
  short* q_nC  = (short*)(base + SZ * 4);
  short* samp  = (short*)(base + SZ * 6);        // dead after gemm_kv
  short* k_blk = (short*)(base + SZ * 8);
  short* v_blk = (short*)(base + SZ * 10);
  short* x1t   = (short*)(base + SZ * 14);       // dead after gemm_q
  short* x2t   = (short*)(base + SZ * 16);
  short* Wqb   = (short*)(base + SZ * 18);
  short* Wkb   = Wqb + C_ * C_;
  short* Wvb   = Wkb + C_ * C_;
  short* Wob   = Wvb + C_ * C_;
  float* dwp   = (float*)(base + SZ * 18 + (size_t)8 * C_ * C_);
  // attention partials reuse dead regions:
  short* op0   = samp;               // SZ bf16
  short* op1   = x1t;                // SZ bf16
  float* lp    = q_dC;               // 2*B*H*NS f32

  dim3 gg(NS_ / 128, C_ / 128, B_);   // (8, 3, 8)

  prep<<<dim3(8461), 256, 0, stream>>>(x1, x2, Wq, Wk, Wv, Wo, off_dw,
                                       x1t, x2t, Wqb, Wkb, Wvb, Wob, dwp);
  gemm_q<<<gg, 256, 0, stream>>>(x1t, Wqb, bq, q_nC, q_dC);
  offsample4<<<dim3(B_ * GROUPS_, 32), 256, 0, stream>>>(
      q_dC, x2t, dwp, off_dwb, ln_g, ln_b, off_w, samp);
  gemm_kv<<<dim3(NS_ / 128, C_ / 64, B_), 256, 0, stream>>>(
      samp, Wkb, Wvb, bk, bv, k_blk, v_blk);
  attn_split<<<dim3(1536), 256, 0, stream>>>(q_nC, k_blk, v_blk, op0, op1, lp);
  gemm_of<<<gg, 256, 0, stream>>>(op0, op1, lp, Wob, bo, x1, (float*)d_out);
}

// Round 16
// 138.968 us; speedup vs baseline: 1.0215x; 1.0215x over previous
//
#include <hip/hip_runtime.h>
#include <math.h>

#define B_  8
#define C_  384
#define NS_ 1024
#define HEADS_ 12
#define HD_ 32
#define GROUPS_ 3
#define CG_ 128
#define EPS_ 1e-5f
// 1/sqrt(32) * log2(e)  (exp computed as exp2)
#define QSC2 (0.17677669529663687f * 1.4426950408889634f)

typedef __attribute__((ext_vector_type(8))) short bf16x8;
typedef __attribute__((ext_vector_type(4))) short bf16x4;
typedef __attribute__((ext_vector_type(4))) float f32x4;
typedef __attribute__((ext_vector_type(8))) __bf16 b8;

static __device__ __forceinline__ short f2b(float f) {
  union { float f; unsigned u; } v; v.f = f;
  unsigned r = v.u + 0x7fffu + ((v.u >> 16) & 1u);   // RNE
  return (short)(r >> 16);
}
static __device__ __forceinline__ float b2f(short s) {
  union { unsigned u; float f; } v; v.u = ((unsigned)(unsigned short)s) << 16;
  return v.f;
}

#if __has_builtin(__builtin_amdgcn_exp2f)
#define EXP2(x) __builtin_amdgcn_exp2f(x)
#else
#define EXP2(x) exp2f(x)
#endif

static __device__ __forceinline__ unsigned cvtpk(float lo, float hi) {
  unsigned r;
  asm("v_cvt_pk_bf16_f32 %0, %1, %2" : "=v"(r) : "v"(lo), "v"(hi));
  return r;
}

static __device__ __forceinline__ f32x4 MFMA(bf16x8 a, bf16x8 b, f32x4 c) {
  return __builtin_amdgcn_mfma_f32_16x16x32_bf16(
      __builtin_bit_cast(b8, a), __builtin_bit_cast(b8, b), c, 0, 0, 0);
}

// ---------------------------------------------------------------------------
// prep mega-kernel (round-13 proven)
// ---------------------------------------------------------------------------
__global__ __launch_bounds__(256) void prep(
    const float* __restrict__ x1, const float* __restrict__ x2,
    const float* __restrict__ Wq, const float* __restrict__ Wk,
    const float* __restrict__ Wv, const float* __restrict__ Wo,
    const float* __restrict__ dw,
    short* __restrict__ x1t, short* __restrict__ x2t,
    short* __restrict__ Wqb, short* __restrict__ Wkb,
    short* __restrict__ Wvb, short* __restrict__ Wob,
    float* __restrict__ dwp) {
  __shared__ float tl[32][33];
  int id = blockIdx.x;
  int tid = threadIdx.x;
  int tx = tid & 31, ty = tid >> 5;
  if (id < 3072) {                       // x1 (8,384,1024) -> (8,1024,384) bf16
    int nb = id & 31, cb = (id >> 5) % 12, b = id / 384;
    int n0 = nb * 32, c0 = cb * 32;
#pragma unroll
    for (int i = 0; i < 4; ++i)
      tl[ty + 8 * i][tx] = x1[((size_t)b * C_ + c0 + ty + 8 * i) * NS_ + n0 + tx];
    __syncthreads();
#pragma unroll
    for (int i = 0; i < 4; ++i)
      x1t[((size_t)b * NS_ + n0 + ty + 8 * i) * C_ + c0 + tx] = f2b(tl[tx][ty + 8 * i]);
  } else if (id < 6144) {                // x2 (24,128,1024) -> (24,1024,128) bf16
    int i = id - 3072;
    int nb = i & 31, cb = (i >> 5) & 3, bg = i / 128;
    int n0 = nb * 32, c0 = cb * 32;
#pragma unroll
    for (int j = 0; j < 4; ++j)
      tl[ty + 8 * j][tx] = x2[((size_t)bg * CG_ + c0 + ty + 8 * j) * NS_ + n0 + tx];
    __syncthreads();
#pragma unroll
    for (int j = 0; j < 4; ++j)
      x2t[((size_t)bg * NS_ + n0 + ty + 8 * j) * CG_ + c0 + tx] = f2b(tl[tx][ty + 8 * j]);
  } else if (id < 8448) {                // weights fp32 -> bf16 (4 x 576 blocks)
    int i = id - 6144;
    int mat = i / 576;
    int e = (i % 576) * 256 + tid;
    const float* s = mat == 0 ? Wq : mat == 1 ? Wk : mat == 2 ? Wv : Wo;
    short*       d = mat == 0 ? Wqb : mat == 1 ? Wkb : mat == 2 ? Wvb : Wob;
    d[e] = f2b(s[e]);
  } else {                               // dw (128,25) -> dwp (25,128)
    int e = (id - 8448) * 256 + tid;
    if (e < 25 * CG_) { int t = e / CG_, c = e % CG_; dwp[e] = dw[c * 25 + t]; }
  }
}

// ---------------------------------------------------------------------------
// K-loop helpers.  4-rt variants (gemm_kv) and 2-rt variants (gemm_q/gemm_of).
// ---------------------------------------------------------------------------
#define GLOADA(kc_, AF)                                                        \
  _Pragma("unroll")                                                            \
  for (int rt = 0; rt < 4; ++rt)                                               \
    AF[rt] = *(const bf16x8*)(Ab + (size_t)(n0 + wr + rt * 16 + r15) * C_ +    \
                              (kc_) + g * 8);
#define GLOADA2(kc_, AF)                                                       \
  _Pragma("unroll")                                                            \
  for (int rt = 0; rt < 2; ++rt)                                               \
    AF[rt] = *(const bf16x8*)(Ab + (size_t)(n0 + wr + rt * 16 + r15) * C_ +    \
                              (kc_) + g * 8);
#define GLOADB(kc_, BF, WP, MOFF)                                              \
  _Pragma("unroll")                                                            \
  for (int ct = 0; ct < 4; ++ct)                                               \
    BF[ct] = *(const bf16x8*)((WP) + (size_t)((MOFF) + ct * 16 + r15) * C_ +   \
                              (kc_) + g * 8);
#define GMFMA(AF, BF)                                                          \
  _Pragma("unroll")                                                            \
  for (int rt = 0; rt < 4; ++rt)                                               \
    _Pragma("unroll")                                                          \
    for (int ct = 0; ct < 4; ++ct) acc[rt][ct] = MFMA(AF[rt], BF[ct], acc[rt][ct]);
#define GMFMA24(AF, BF)                                                        \
  _Pragma("unroll")                                                            \
  for (int rt = 0; rt < 2; ++rt)                                               \
    _Pragma("unroll")                                                          \
    for (int ct = 0; ct < 4; ++ct) acc[rt][ct] = MFMA(AF[rt], BF[ct], acc[rt][ct]);

// ---------------------------------------------------------------------------
// Q-projection GEMM, 64n x 128m tile (grid 16x3x8 = 384 blocks, 1.5/CU).
// Wave = 32n x 64m, acc[2][4].
// ---------------------------------------------------------------------------
__global__ __launch_bounds__(256) void gemm_q(
    const short* __restrict__ A, const short* __restrict__ Wb,
    const float* __restrict__ bias, short* __restrict__ outb,
    float* __restrict__ outf) {
  int b = blockIdx.z;
  int n0 = blockIdx.x * 64;
  int m0 = blockIdx.y * 128;
  int wv = threadIdx.x >> 6;
  int lane = threadIdx.x & 63;
  int g = lane >> 4, r15 = lane & 15;
  int wr = (wv >> 1) * 32, wc = (wv & 1) * 64;

  const short* Ab = A + (size_t)b * NS_ * C_;
  f32x4 acc[2][4];
#pragma unroll
  for (int i = 0; i < 2; ++i)
#pragma unroll
    for (int j = 0; j < 4; ++j) acc[i][j] = (f32x4){0.f, 0.f, 0.f, 0.f};

  bf16x8 afA[2], bfA[4], afB[2], bfB[4];
  GLOADA2(0, afA); GLOADB(0, bfA, Wb, m0 + wc);
#pragma unroll
  for (int cp = 0; cp < 6; ++cp) {
    GLOADA2(64 * cp + 32, afB); GLOADB(64 * cp + 32, bfB, Wb, m0 + wc);
    GMFMA24(afA, bfA);
    if (cp < 5) { GLOADA2(64 * cp + 64, afA); GLOADB(64 * cp + 64, bfA, Wb, m0 + wc); }
    GMFMA24(afB, bfB);
  }

#pragma unroll
  for (int rt = 0; rt < 2; ++rt)
#pragma unroll
    for (int ct = 0; ct < 4; ++ct) {
      int m = m0 + wc + ct * 16 + r15;
      int nb = n0 + wr + rt * 16 + g * 4;
      float bv = bias[m];
      f32x4 v = acc[rt][ct];
      v.x += bv; v.y += bv; v.z += bv; v.w += bv;
      *(f32x4*)(outf + ((size_t)b * C_ + m) * NS_ + nb) = v;
      outb[((size_t)b * NS_ + nb + 0) * C_ + m] = f2b(v.x * QSC2);
      outb[((size_t)b * NS_ + nb + 1) * C_ + m] = f2b(v.y * QSC2);
      outb[((size_t)b * NS_ + nb + 2) * C_ + m] = f2b(v.z * QSC2);
      outb[((size_t)b * NS_ + nb + 3) * C_ + m] = f2b(v.w * QSC2);
    }
}

// ---------------------------------------------------------------------------
// Output GEMM with inline attention-merge, 64n x 128m tile (384 blocks).
// Only 2 merge-fragments per chunk per wave (half the round-15 chain).
// ---------------------------------------------------------------------------
#define GLOADAM2(kc_, AF)                                                      \
  _Pragma("unroll")                                                            \
  for (int rt = 0; rt < 2; ++rt) {                                             \
    int n_ = n0 + wr + rt * 16 + r15;                                          \
    size_t off_ = ((size_t)bz * NS_ + n_) * C_ + (kc_) + g * 8;                \
    bf16x8 a0_ = *(const bf16x8*)(op0 + off_);                                 \
    bf16x8 a1_ = *(const bf16x8*)(op1 + off_);                                 \
    int h_ = (kc_) >> 5;                                                       \
    float l_ = lp[((size_t)(bz * HEADS_) + h_) * NS_ + n_] +                   \
               lp[((size_t)((B_ + bz) * HEADS_) + h_) * NS_ + n_];             \
    float rl_ = 1.f / l_;                                                      \
    union { unsigned u[4]; bf16x8 v; } r_;                                     \
    _Pragma("unroll")                                                          \
    for (int j2 = 0; j2 < 4; ++j2)                                             \
      r_.u[j2] = cvtpk((b2f(a0_[2 * j2]) + b2f(a1_[2 * j2])) * rl_,            \
                       (b2f(a0_[2 * j2 + 1]) + b2f(a1_[2 * j2 + 1])) * rl_);   \
    AF[rt] = r_.v;                                                             \
  }

__global__ __launch_bounds__(256) void gemm_of(
    const short* __restrict__ op0, const short* __restrict__ op1,
    const float* __restrict__ lp, const short* __restrict__ Wb,
    const float* __restrict__ bias, const float* __restrict__ res,
    float* __restrict__ outf) {
  int bz = blockIdx.z;
  int n0 = blockIdx.x * 64;
  int m0 = blockIdx.y * 128;
  int wv = threadIdx.x >> 6;
  int lane = threadIdx.x & 63;
  int g = lane >> 4, r15 = lane & 15;
  int wr = (wv >> 1) * 32, wc = (wv & 1) * 64;

  f32x4 acc[2][4];
#pragma unroll
  for (int i = 0; i < 2; ++i)
#pragma unroll
    for (int j = 0; j < 4; ++j) acc[i][j] = (f32x4){0.f, 0.f, 0.f, 0.f};

  bf16x8 afA[2], bfA[4], afB[2], bfB[4];
  GLOADAM2(0, afA); GLOADB(0, bfA, Wb, m0 + wc);
#pragma unroll
  for (int cp = 0; cp < 6; ++cp) {
    GLOADAM2(64 * cp + 32, afB); GLOADB(64 * cp + 32, bfB, Wb, m0 + wc);
    GMFMA24(afA, bfA);
    if (cp < 5) { GLOADAM2(64 * cp + 64, afA); GLOADB(64 * cp + 64, bfA, Wb, m0 + wc); }
    GMFMA24(afB, bfB);
  }

#pragma unroll
  for (int rt = 0; rt < 2; ++rt)
#pragma unroll
    for (int ct = 0; ct < 4; ++ct) {
      int m = m0 + wc + ct * 16 + r15;
      int nb = n0 + wr + rt * 16 + g * 4;
      float bv = bias[m];
      f32x4 v = acc[rt][ct];
      const f32x4 rv = *(const f32x4*)(res + ((size_t)bz * C_ + m) * NS_ + nb);
      v.x += bv + rv.x; v.y += bv + rv.y; v.z += bv + rv.z; v.w += bv + rv.w;
      *(f32x4*)(outf + ((size_t)bz * C_ + m) * NS_ + nb) = v;
    }
}

// ---------------------------------------------------------------------------
// Fused K+V projection GEMM (round-13 proven, unchanged).
// ---------------------------------------------------------------------------
__global__ __launch_bounds__(256) void gemm_kv(
    const short* __restrict__ A, const short* __restrict__ Wkb,
    const short* __restrict__ Wvb, const float* __restrict__ bkv,
    const float* __restrict__ bvv, short* __restrict__ kblk,
    short* __restrict__ vblk) {
  int b = blockIdx.z;
  int n0 = blockIdx.x * 128;
  int m0 = blockIdx.y * 64;
  int wv = threadIdx.x >> 6;
  int lane = threadIdx.x & 63;
  int g = lane >> 4, r15 = lane & 15;
  int wr = (wv >> 1) * 64;
  int isv = wv & 1;
  const short* Wsel = isv ? Wvb : Wkb;
  const float* bsel = isv ? bvv : bkv;

  const short* Ab = A + (size_t)b * NS_ * C_;
  f32x4 acc[4][4];
#pragma unroll
  for (int i = 0; i < 4; ++i)
#pragma unroll
    for (int j = 0; j < 4; ++j) acc[i][j] = (f32x4){0.f, 0.f, 0.f, 0.f};

  bf16x8 afA[4], bfA[4], afB[4], bfB[4];
  GLOADA(0, afA); GLOADB(0, bfA, Wsel, m0);
#pragma unroll
  for (int cp = 0; cp < 6; ++cp) {
    GLOADA(64 * cp + 32, afB); GLOADB(64 * cp + 32, bfB, Wsel, m0);
    GMFMA(afA, bfA);
    if (cp < 5) { GLOADA(64 * cp + 64, afA); GLOADB(64 * cp + 64, bfA, Wsel, m0); }
    GMFMA(afB, bfB);
  }

#pragma unroll
  for (int rt = 0; rt < 4; ++rt)
#pragma unroll
    for (int ct = 0; ct < 4; ++ct) {
      int m = m0 + ct * 16 + r15;
      int nb = n0 + wr + rt * 16 + g * 4;
      float bv = bsel[m];
      f32x4 v = acc[rt][ct];
      v.x += bv; v.y += bv; v.z += bv; v.w += bv;
      int h = m >> 5, dh = m & 31;
      if (!isv) {
        size_t hb = ((size_t)(b * HEADS_ + h) * 32 + (nb >> 5)) * 1024 +
                    (((nb >> 4) & 1) ? 512 : 0);
        int base_l = (nb & 15) | ((dh >> 3) << 4);
        int jj = dh & 7;
        kblk[hb + (size_t)(base_l + 0) * 8 + jj] = f2b(v.x);
        kblk[hb + (size_t)(base_l + 1) * 8 + jj] = f2b(v.y);
        kblk[hb + (size_t)(base_l + 2) * 8 + jj] = f2b(v.z);
        kblk[hb + (size_t)(base_l + 3) * 8 + jj] = f2b(v.w);
      } else {
        int dt = dh >> 4, q15v = dh & 15;
        int kk = nb & 31;
        int half = kk >> 4, gk = (kk & 15) >> 2;
        size_t off = ((size_t)(b * HEADS_ + h) * 32 + (nb >> 5)) * 1024 +
                     dt * 512 + (size_t)((q15v | (gk << 4))) * 8 + half * 4;
        bf16x4 s4 = {f2b(v.x), f2b(v.y), f2b(v.z), f2b(v.w)};
        *(bf16x4*)(vblk + off) = s4;
      }
    }
}

// ---------------------------------------------------------------------------
// offsample4 (round-13 proven)
// ---------------------------------------------------------------------------
__global__ __launch_bounds__(256) void offsample4(
    const float* __restrict__ qd, const short* __restrict__ x2t,
    const float* __restrict__ dwp, const float* __restrict__ dwb,
    const float* __restrict__ lng, const float* __restrict__ lnb,
    const float* __restrict__ offw, short* __restrict__ samp) {
  int bg = blockIdx.x, y = blockIdx.y;
  int tid = threadIdx.x;
  int xg = tid >> 5, cc = tid & 31;
  int x0 = xg << 2, c0 = cc << 2;

  const float* qb = qd + ((size_t)bg * CG_ + c0) * NS_;

  f32x4 dwb4 = *(const f32x4*)(dwb + c0);
  float a[4][4];
#pragma unroll
  for (int i = 0; i < 4; ++i)
#pragma unroll
    for (int p = 0; p < 4; ++p) a[i][p] = dwb4[i];

#pragma unroll
  for (int dy = -2; dy <= 2; ++dy) {
    int yy = y + dy;
    if (yy < 0 || yy > 31) continue;
    f32x4 w0 = *(const f32x4*)(dwp + ((dy + 2) * 5 + 0) * CG_ + c0);
    f32x4 w1 = *(const f32x4*)(dwp + ((dy + 2) * 5 + 1) * CG_ + c0);
    f32x4 w2 = *(const f32x4*)(dwp + ((dy + 2) * 5 + 2) * CG_ + c0);
    f32x4 w3 = *(const f32x4*)(dwp + ((dy + 2) * 5 + 3) * CG_ + c0);
    f32x4 w4 = *(const f32x4*)(dwp + ((dy + 2) * 5 + 4) * CG_ + c0);
#pragma unroll
    for (int i = 0; i < 4; ++i) {
      const float* row = qb + (size_t)i * NS_ + yy * 32;
      f32x4 wa = (f32x4){0.f, 0.f, 0.f, 0.f};
      f32x4 wcv = (f32x4){0.f, 0.f, 0.f, 0.f};
      if (x0 >= 4)  wa  = *(const f32x4*)(row + x0 - 4);
      f32x4 wb = *(const f32x4*)(row + x0);
      if (x0 <= 24) wcv = *(const f32x4*)(row + x0 + 4);
      float w[12] = {wa[0], wa[1], wa[2], wa[3], wb[0], wb[1], wb[2], wb[3],
                     wcv[0], wcv[1], wcv[2], wcv[3]};
      float wt[5] = {w0[i], w1[i], w2[i], w3[i], w4[i]};
#pragma unroll
      for (int p = 0; p < 4; ++p)
#pragma unroll
        for (int j = 0; j < 5; ++j)
          a[i][p] = fmaf(w[p + j + 2], wt[j], a[i][p]);
    }
  }

  f32x4 sum = (f32x4){0.f, 0.f, 0.f, 0.f}, sumsq = sum;
#pragma unroll
  for (int i = 0; i < 4; ++i)
#pragma unroll
    for (int p = 0; p < 4; ++p) { sum[p] += a[i][p]; sumsq[p] += a[i][p] * a[i][p]; }
#pragma unroll
  for (int m = 1; m <= 16; m <<= 1) {
#pragma unroll
    for (int p = 0; p < 4; ++p) {
      sum[p]   += __shfl_xor(sum[p], m);
      sumsq[p] += __shfl_xor(sumsq[p], m);
    }
  }
  f32x4 mu, rs;
#pragma unroll
  for (int p = 0; p < 4; ++p) {
    mu[p] = sum[p] * (1.f / CG_);
    float var = sumsq[p] * (1.f / CG_) - mu[p] * mu[p];
    rs[p] = rsqrtf(var + EPS_);
  }

  f32x4 lg = *(const f32x4*)(lng + c0);
  f32x4 lb = *(const f32x4*)(lnb + c0);
  f32x4 ow0 = *(const f32x4*)(offw + c0);
  f32x4 ow1 = *(const f32x4*)(offw + CG_ + c0);
  f32x4 o0 = (f32x4){0.f, 0.f, 0.f, 0.f}, o1 = o0;
#pragma unroll
  for (int i = 0; i < 4; ++i)
#pragma unroll
    for (int p = 0; p < 4; ++p) {
      float z = (a[i][p] - mu[p]) * rs[p] * lg[i] + lb[i];
      float u = z * fmaf(0.044715f * z, z, 1.f);
      float e = __expf(-1.5957691216057308f * u);
      float ge = z * __builtin_amdgcn_rcpf(1.f + e);
      o0[p] = fmaf(ow0[i], ge, o0[p]);
      o1[p] = fmaf(ow1[i], ge, o1[p]);
    }
#pragma unroll
  for (int m = 1; m <= 16; m <<= 1) {
#pragma unroll
    for (int p = 0; p < 4; ++p) {
      o0[p] += __shfl_xor(o0[p], m);
      o1[p] += __shfl_xor(o1[p], m);
    }
  }

  int b = bg / GROUPS_, gi = bg % GROUPS_;
  const short* xb = x2t + (size_t)bg * NS_ * CG_ + c0;
  float gy = (y + 0.5f) * 0.0625f - 1.f;
#pragma unroll
  for (int p = 0; p < 4; ++p) {
    int x = x0 + p, n = y * 32 + x;
    float gx = (x + 0.5f) * 0.0625f - 1.f;
    float px = fminf(fmaxf(o0[p] + gx, -1.f), 1.f);
    float py = fminf(fmaxf(o1[p] + gy, -1.f), 1.f);
    float ix = (px + 1.f) * 0.5f * 31.f;
    float iy = (py + 1.f) * 0.5f * 31.f;
    float x0f = floorf(ix), y0f = floorf(iy);
    float wx = ix - x0f, wy = iy - y0f;
    int xa = min(max((int)x0f, 0), 31), xbb = min(xa + 1, 31);
    int ya = min(max((int)y0f, 0), 31), yb = min(ya + 1, 31);
    int i00 = ya * 32 + xa, i01 = ya * 32 + xbb;
    int i10 = yb * 32 + xa, i11 = yb * 32 + xbb;
    float w00 = (1.f - wx) * (1.f - wy), w01 = wx * (1.f - wy);
    float w10 = (1.f - wx) * wy,         w11 = wx * wy;
    bf16x4 v00 = *(const bf16x4*)(xb + (size_t)i00 * CG_);
    bf16x4 v01 = *(const bf16x4*)(xb + (size_t)i01 * CG_);
    bf16x4 v10 = *(const bf16x4*)(xb + (size_t)i10 * CG_);
    bf16x4 v11 = *(const bf16x4*)(xb + (size_t)i11 * CG_);
    short out4[4];
#pragma unroll
    for (int j = 0; j < 4; ++j) {
      float v = w00 * b2f(v00[j]) + w01 * b2f(v01[j]) +
                w10 * b2f(v10[j]) + w11 * b2f(v11[j]);
      out4[j] = f2b(v);
    }
    *(bf16x4*)(samp + ((size_t)b * NS_ + n) * C_ + gi * CG_ + c0) = *(bf16x4*)out4;
  }
}

// ---------------------------------------------------------------------------
// Blocked-layout split-K attention (round-13 proven 2-fragment version):
// 16 chunks/wave, grid 1536, XCD-locality swizzle, 1-deep A/B prefetch.
// VGPR ~104 -> 4+ waves/SIMD. (4-fragment variant hits VGPR 236 — don't.)
// ---------------------------------------------------------------------------
__global__ __launch_bounds__(256) void attn_split(
    const short* __restrict__ qn, const short* __restrict__ kblk,
    const short* __restrict__ vblk, short* __restrict__ op0,
    short* __restrict__ op1, float* __restrict__ lp) {
  // grid 1536: L = (task%8) + 8*((task/8) + 24*qblk); task = bh*2+s
  int L = blockIdx.x;
  int tq = L >> 3;
  int task = (L & 7) + ((tq % 24) << 3);   // 0..191
  int qblk = tq / 24;                      // 0..7
  int bh = task >> 1, s = task & 1;
  int b = bh / HEADS_, h = bh % HEADS_;
  int wv = threadIdx.x >> 6, lane = threadIdx.x & 63;
  int g = lane >> 4, q15 = lane & 15;
  int q0 = qblk * 128 + wv * 32;

  const short* Qb = qn + (size_t)b * NS_ * C_ + h * HD_;
  const short* Kc = kblk + ((size_t)(b * HEADS_ + h) * 32 + s * 16) * 1024 + lane * 8;
  const short* Vc = vblk + ((size_t)(b * HEADS_ + h) * 32 + s * 16) * 1024 + lane * 8;

  bf16x8 qf[2];
  qf[0] = *(const bf16x8*)(Qb + (size_t)(q0 + q15) * C_ + g * 8);
  qf[1] = *(const bf16x8*)(Qb + (size_t)(q0 + 16 + q15) * C_ + g * 8);

  f32x4 o[2][2];
  o[0][0] = o[0][1] = o[1][0] = o[1][1] = (f32x4){0.f, 0.f, 0.f, 0.f};
  f32x4 lv[2];
  lv[0] = lv[1] = (f32x4){0.f, 0.f, 0.f, 0.f};

#define LOADC(c_, K0, K1, V0, V1)                                              \
  {                                                                            \
    K0 = *(const bf16x8*)(Kc + (c_) * 1024);                                   \
    K1 = *(const bf16x8*)(Kc + (c_) * 1024 + 512);                             \
    V0 = *(const bf16x8*)(Vc + (c_) * 1024);                                   \
    V1 = *(const bf16x8*)(Vc + (c_) * 1024 + 512);                             \
  }

#define COMPUTEC(K0, K1, V0, V1)                                               \
  {                                                                            \
    _Pragma("unroll")                                                          \
    for (int qt = 0; qt < 2; ++qt) {                                           \
      f32x4 z_ = {0.f, 0.f, 0.f, 0.f};                                         \
      f32x4 t0 = MFMA(K0, qf[qt], z_);                                         \
      f32x4 t1 = MFMA(K1, qf[qt], z_);                                         \
      f32x4 e0, e1;                                                            \
      e0.x = EXP2(t0.x); e0.y = EXP2(t0.y); e0.z = EXP2(t0.z); e0.w = EXP2(t0.w);\
      e1.x = EXP2(t1.x); e1.y = EXP2(t1.y); e1.z = EXP2(t1.z); e1.w = EXP2(t1.w);\
      lv[qt] += e0; lv[qt] += e1;                                              \
      union { unsigned u[4]; bf16x8 v; } pu;                                   \
      pu.u[0] = cvtpk(e0.x, e0.y);                                             \
      pu.u[1] = cvtpk(e0.z, e0.w);                                             \
      pu.u[2] = cvtpk(e1.x, e1.y);                                             \
      pu.u[3] = cvtpk(e1.z, e1.w);                                             \
      o[qt][0] = MFMA(V0, pu.v, o[qt][0]);                                     \
      o[qt][1] = MFMA(V1, pu.v, o[qt][1]);                                     \
    }                                                                          \
  }

  bf16x8 kA0, kA1, vA0, vA1, kB0, kB1, vB0, vB1;
  LOADC(0, kA0, kA1, vA0, vA1);
#pragma unroll
  for (int cp = 0; cp < 8; ++cp) {
    LOADC(2 * cp + 1, kB0, kB1, vB0, vB1);
    COMPUTEC(kA0, kA1, vA0, vA1);
    if (cp < 7) LOADC(2 * cp + 2, kA0, kA1, vA0, vA1);
    COMPUTEC(kB0, kB1, vB0, vB1);
  }
#undef LOADC
#undef COMPUTEC

  short* opS = s ? op1 : op0;
#pragma unroll
  for (int qt = 0; qt < 2; ++qt) {
    float lt = (lv[qt].x + lv[qt].y) + (lv[qt].z + lv[qt].w);
    lt += __shfl_xor(lt, 16);
    lt += __shfl_xor(lt, 32);
    int q = q0 + qt * 16 + q15;
    if (g == 0) lp[((size_t)(s * B_ + b) * HEADS_ + h) * NS_ + q] = lt;
#pragma unroll
    for (int dt = 0; dt < 2; ++dt) {
      f32x4 ov = o[qt][dt];
      bf16x4 s4 = {f2b(ov.x), f2b(ov.y), f2b(ov.z), f2b(ov.w)};
      *(bf16x4*)(opS + ((size_t)b * NS_ + q) * C_ + h * HD_ + dt * 16 + g * 4) = s4;
    }
  }
}

// ---------------------------------------------------------------------------
extern "C" void kernel_launch(void* const* d_in, const int* in_sizes, int n_in,
                              void* d_out, int out_size, void* d_ws, size_t ws_size,
                              hipStream_t stream) {
  const float* x1      = (const float*)d_in[0];
  const float* x2      = (const float*)d_in[1];
  const float* Wq      = (const float*)d_in[2];
  const float* bq      = (const float*)d_in[3];
  const float* Wk      = (const float*)d_in[4];
  const float* bk      = (const float*)d_in[5];
  const float* Wv      = (const float*)d_in[6];
  const float* bv      = (const float*)d_in[7];
  const float* Wo      = (const float*)d_in[8];
  const float* bo      = (const float*)d_in[9];
  const float* off_dw  = (const float*)d_in[10];
  const float* off_dwb = (const float*)d_in[11];
  const float* ln_g    = (const float*)d_in[12];
  const float* ln_b    = (const float*)d_in[13];
  const float* off_w   = (const float*)d_in[14];

  char* base = (char*)d_ws;
  const size_t SZ = (size_t)B_ * C_ * NS_;
  float* q_dC  = (float*)base;                   // f32, dead after offsample4
  short* q_nC  = (short*)(base + SZ * 4);
  short* samp  = (short*)(base + SZ * 6);        // dead after gemm_kv
  short* k_blk = (short*)(base + SZ * 8);
  short* v_blk = (short*)(base + SZ * 10);
  short* x1t   = (short*)(base + SZ * 14);       // dead after gemm_q
  short* x2t   = (short*)(base + SZ * 16);
  short* Wqb   = (short*)(base + SZ * 18);
  short* Wkb   = Wqb + C_ * C_;
  short* Wvb   = Wkb + C_ * C_;
  short* Wob   = Wvb + C_ * C_;
  float* dwp   = (float*)(base + SZ * 18 + (size_t)8 * C_ * C_);
  // attention partials reuse dead regions:
  short* op0   = samp;               // SZ bf16
  short* op1   = x1t;                // SZ bf16
  float* lp    = q_dC;               // 2*B*H*NS f32

  dim3 gg2(NS_ / 64, C_ / 128, B_);   // (16, 3, 8) = 384 blocks

  prep<<<dim3(8461), 256, 0, stream>>>(x1, x2, Wq, Wk, Wv, Wo, off_dw,
                                       x1t, x2t, Wqb, Wkb, Wvb, Wob, dwp);
  gemm_q<<<gg2, 256, 0, stream>>>(x1t, Wqb, bq, q_nC, q_dC);
  offsample4<<<dim3(B_ * GROUPS_, 32), 256, 0, stream>>>(
      q_dC, x2t, dwp, off_dwb, ln_g, ln_b, off_w, samp);
  gemm_kv<<<dim3(NS_ / 128, C_ / 64, B_), 256, 0, stream>>>(
      samp, Wkb, Wvb, bk, bv, k_blk, v_blk);
  attn_split<<<dim3(1536), 256, 0, stream>>>(q_nC, k_blk, v_blk, op0, op1, lp);
  gemm_of<<<gg2, 256, 0, stream>>>(op0, op1, lp, Wob, bo, x1, (float*)d_out);
}

// Round 17
// 138.324 us; speedup vs baseline: 1.0262x; 1.0047x over previous
//
#include <hip/hip_runtime.h>
#include <math.h>

#define B_  8
#define C_  384
#define NS_ 1024
#define HEADS_ 12
#define HD_ 32
#define GROUPS_ 3
#define CG_ 128
#define EPS_ 1e-5f
// 1/sqrt(32) * log2(e)  (exp computed as exp2)
#define QSC2 (0.17677669529663687f * 1.4426950408889634f)

typedef __attribute__((ext_vector_type(8))) short bf16x8;
typedef __attribute__((ext_vector_type(4))) short bf16x4;
typedef __attribute__((ext_vector_type(4))) float f32x4;
typedef __attribute__((ext_vector_type(8))) __bf16 b8;

static __device__ __forceinline__ short f2b(float f) {
  union { float f; unsigned u; } v; v.f = f;
  unsigned r = v.u + 0x7fffu + ((v.u >> 16) & 1u);   // RNE
  return (short)(r >> 16);
}
static __device__ __forceinline__ float b2f(short s) {
  union { unsigned u; float f; } v; v.u = ((unsigned)(unsigned short)s) << 16;
  return v.f;
}

#if __has_builtin(__builtin_amdgcn_exp2f)
#define EXP2(x) __builtin_amdgcn_exp2f(x)
#else
#define EXP2(x) exp2f(x)
#endif

static __device__ __forceinline__ unsigned cvtpk(float lo, float hi) {
  unsigned r;
  asm("v_cvt_pk_bf16_f32 %0, %1, %2" : "=v"(r) : "v"(lo), "v"(hi));
  return r;
}

static __device__ __forceinline__ f32x4 MFMA(bf16x8 a, bf16x8 b, f32x4 c) {
  return __builtin_amdgcn_mfma_f32_16x16x32_bf16(
      __builtin_bit_cast(b8, a), __builtin_bit_cast(b8, b), c, 0, 0, 0);
}

// ---------------------------------------------------------------------------
// prep mega-kernel (round-13 proven)
// ---------------------------------------------------------------------------
__global__ __launch_bounds__(256) void prep(
    const float* __restrict__ x1, const float* __restrict__ x2,
    const float* __restrict__ Wq, const float* __restrict__ Wk,
    const float* __restrict__ Wv, const float* __restrict__ Wo,
    const float* __restrict__ dw,
    short* __restrict__ x1t, short* __restrict__ x2t,
    short* __restrict__ Wqb, short* __restrict__ Wkb,
    short* __restrict__ Wvb, short* __restrict__ Wob,
    float* __restrict__ dwp) {
  __shared__ float tl[32][33];
  int id = blockIdx.x;
  int tid = threadIdx.x;
  int tx = tid & 31, ty = tid >> 5;
  if (id < 3072) {                       // x1 (8,384,1024) -> (8,1024,384) bf16
    int nb = id & 31, cb = (id >> 5) % 12, b = id / 384;
    int n0 = nb * 32, c0 = cb * 32;
#pragma unroll
    for (int i = 0; i < 4; ++i)
      tl[ty + 8 * i][tx] = x1[((size_t)b * C_ + c0 + ty + 8 * i) * NS_ + n0 + tx];
    __syncthreads();
#pragma unroll
    for (int i = 0; i < 4; ++i)
      x1t[((size_t)b * NS_ + n0 + ty + 8 * i) * C_ + c0 + tx] = f2b(tl[tx][ty + 8 * i]);
  } else if (id < 6144) {                // x2 (24,128,1024) -> (24,1024,128) bf16
    int i = id - 3072;
    int nb = i & 31, cb = (i >> 5) & 3, bg = i / 128;
    int n0 = nb * 32, c0 = cb * 32;
#pragma unroll
    for (int j = 0; j < 4; ++j)
      tl[ty + 8 * j][tx] = x2[((size_t)bg * CG_ + c0 + ty + 8 * j) * NS_ + n0 + tx];
    __syncthreads();
#pragma unroll
    for (int j = 0; j < 4; ++j)
      x2t[((size_t)bg * NS_ + n0 + ty + 8 * j) * CG_ + c0 + tx] = f2b(tl[tx][ty + 8 * j]);
  } else if (id < 8448) {                // weights fp32 -> bf16 (4 x 576 blocks)
    int i = id - 6144;
    int mat = i / 576;
    int e = (i % 576) * 256 + tid;
    const float* s = mat == 0 ? Wq : mat == 1 ? Wk : mat == 2 ? Wv : Wo;
    short*       d = mat == 0 ? Wqb : mat == 1 ? Wkb : mat == 2 ? Wvb : Wob;
    d[e] = f2b(s[e]);
  } else {                               // dw (128,25) -> dwp (25,128)
    int e = (id - 8448) * 256 + tid;
    if (e < 25 * CG_) { int t = e / CG_, c = e % CG_; dwp[e] = dw[c * 25 + t]; }
  }
}

// ---------------------------------------------------------------------------
// K-loop helpers: 4-rt (gemm_kv) and 2-rt (gemm_nm) variants.
// ---------------------------------------------------------------------------
#define GLOADA(kc_, AF)                                                        \
  _Pragma("unroll")                                                            \
  for (int rt = 0; rt < 4; ++rt)                                               \
    AF[rt] = *(const bf16x8*)(Ab + (size_t)(n0 + wr + rt * 16 + r15) * C_ +    \
                              (kc_) + g * 8);
#define GLOADA2(kc_, AF)                                                       \
  _Pragma("unroll")                                                            \
  for (int rt = 0; rt < 2; ++rt)                                               \
    AF[rt] = *(const bf16x8*)(Ab + (size_t)(n0 + wr + rt * 16 + r15) * C_ +    \
                              (kc_) + g * 8);
#define GLOADB(kc_, BF, WP, MOFF)                                              \
  _Pragma("unroll")                                                            \
  for (int ct = 0; ct < 4; ++ct)                                               \
    BF[ct] = *(const bf16x8*)((WP) + (size_t)((MOFF) + ct * 16 + r15) * C_ +   \
                              (kc_) + g * 8);
#define GMFMA(AF, BF)                                                          \
  _Pragma("unroll")                                                            \
  for (int rt = 0; rt < 4; ++rt)                                               \
    _Pragma("unroll")                                                          \
    for (int ct = 0; ct < 4; ++ct) acc[rt][ct] = MFMA(AF[rt], BF[ct], acc[rt][ct]);
#define GMFMA24(AF, BF)                                                        \
  _Pragma("unroll")                                                            \
  for (int rt = 0; rt < 2; ++rt)                                               \
    _Pragma("unroll")                                                          \
    for (int ct = 0; ct < 4; ++ct) acc[rt][ct] = MFMA(AF[rt], BF[ct], acc[rt][ct]);

// ---------------------------------------------------------------------------
// MFMA GEMM, 64n x 128m tile (grid (16,3,8) = 384 blocks, 1.5/CU).
// Wave = 32n x 64m, acc[2][4]. 1-deep prefetch.
// MODE 1: outf d-major f32, outb n-major bf16 * QSC2    (q projection)
// MODE 3: outf d-major f32 + res      (final projection + residual)
// ---------------------------------------------------------------------------
template <int MODE>
__global__ __launch_bounds__(256) void gemm_nm(
    const short* __restrict__ A, const short* __restrict__ Wb,
    const float* __restrict__ bias, const float* __restrict__ res,
    short* __restrict__ outb, float* __restrict__ outf) {
  int b = blockIdx.z;
  int n0 = blockIdx.x * 64;
  int m0 = blockIdx.y * 128;
  int wv = threadIdx.x >> 6;
  int lane = threadIdx.x & 63;
  int g = lane >> 4, r15 = lane & 15;
  int wr = (wv >> 1) * 32, wc = (wv & 1) * 64;

  const short* Ab = A + (size_t)b * NS_ * C_;
  f32x4 acc[2][4];
#pragma unroll
  for (int i = 0; i < 2; ++i)
#pragma unroll
    for (int j = 0; j < 4; ++j) acc[i][j] = (f32x4){0.f, 0.f, 0.f, 0.f};

  bf16x8 afA[2], bfA[4], afB[2], bfB[4];
  GLOADA2(0, afA); GLOADB(0, bfA, Wb, m0 + wc);
#pragma unroll
  for (int cp = 0; cp < 6; ++cp) {
    GLOADA2(64 * cp + 32, afB); GLOADB(64 * cp + 32, bfB, Wb, m0 + wc);
    GMFMA24(afA, bfA);
    if (cp < 5) { GLOADA2(64 * cp + 64, afA); GLOADB(64 * cp + 64, bfA, Wb, m0 + wc); }
    GMFMA24(afB, bfB);
  }

#pragma unroll
  for (int rt = 0; rt < 2; ++rt)
#pragma unroll
    for (int ct = 0; ct < 4; ++ct) {
      int m = m0 + wc + ct * 16 + r15;
      int nb = n0 + wr + rt * 16 + g * 4;
      float bv = bias[m];
      f32x4 v = acc[rt][ct];
      v.x += bv; v.y += bv; v.z += bv; v.w += bv;
      if (MODE == 1) {
        *(f32x4*)(outf + ((size_t)b * C_ + m) * NS_ + nb) = v;
        outb[((size_t)b * NS_ + nb + 0) * C_ + m] = f2b(v.x * QSC2);
        outb[((size_t)b * NS_ + nb + 1) * C_ + m] = f2b(v.y * QSC2);
        outb[((size_t)b * NS_ + nb + 2) * C_ + m] = f2b(v.z * QSC2);
        outb[((size_t)b * NS_ + nb + 3) * C_ + m] = f2b(v.w * QSC2);
      } else {
        const f32x4 rv = *(const f32x4*)(res + ((size_t)b * C_ + m) * NS_ + nb);
        v.x += rv.x; v.y += rv.y; v.z += rv.z; v.w += rv.w;
        *(f32x4*)(outf + ((size_t)b * C_ + m) * NS_ + nb) = v;
      }
    }
}

// ---------------------------------------------------------------------------
// Fused K+V projection GEMM (round-13 proven, unchanged).
// ---------------------------------------------------------------------------
__global__ __launch_bounds__(256) void gemm_kv(
    const short* __restrict__ A, const short* __restrict__ Wkb,
    const short* __restrict__ Wvb, const float* __restrict__ bkv,
    const float* __restrict__ bvv, short* __restrict__ kblk,
    short* __restrict__ vblk) {
  int b = blockIdx.z;
  int n0 = blockIdx.x * 128;
  int m0 = blockIdx.y * 64;
  int wv = threadIdx.x >> 6;
  int lane = threadIdx.x & 63;
  int g = lane >> 4, r15 = lane & 15;
  int wr = (wv >> 1) * 64;
  int isv = wv & 1;
  const short* Wsel = isv ? Wvb : Wkb;
  const float* bsel = isv ? bvv : bkv;

  const short* Ab = A + (size_t)b * NS_ * C_;
  f32x4 acc[4][4];
#pragma unroll
  for (int i = 0; i < 4; ++i)
#pragma unroll
    for (int j = 0; j < 4; ++j) acc[i][j] = (f32x4){0.f, 0.f, 0.f, 0.f};

  bf16x8 afA[4], bfA[4], afB[4], bfB[4];
  GLOADA(0, afA); GLOADB(0, bfA, Wsel, m0);
#pragma unroll
  for (int cp = 0; cp < 6; ++cp) {
    GLOADA(64 * cp + 32, afB); GLOADB(64 * cp + 32, bfB, Wsel, m0);
    GMFMA(afA, bfA);
    if (cp < 5) { GLOADA(64 * cp + 64, afA); GLOADB(64 * cp + 64, bfA, Wsel, m0); }
    GMFMA(afB, bfB);
  }

#pragma unroll
  for (int rt = 0; rt < 4; ++rt)
#pragma unroll
    for (int ct = 0; ct < 4; ++ct) {
      int m = m0 + ct * 16 + r15;
      int nb = n0 + wr + rt * 16 + g * 4;
      float bv = bsel[m];
      f32x4 v = acc[rt][ct];
      v.x += bv; v.y += bv; v.z += bv; v.w += bv;
      int h = m >> 5, dh = m & 31;
      if (!isv) {
        size_t hb = ((size_t)(b * HEADS_ + h) * 32 + (nb >> 5)) * 1024 +
                    (((nb >> 4) & 1) ? 512 : 0);
        int base_l = (nb & 15) | ((dh >> 3) << 4);
        int jj = dh & 7;
        kblk[hb + (size_t)(base_l + 0) * 8 + jj] = f2b(v.x);
        kblk[hb + (size_t)(base_l + 1) * 8 + jj] = f2b(v.y);
        kblk[hb + (size_t)(base_l + 2) * 8 + jj] = f2b(v.z);
        kblk[hb + (size_t)(base_l + 3) * 8 + jj] = f2b(v.w);
      } else {
        int dt = dh >> 4, q15v = dh & 15;
        int kk = nb & 31;
        int half = kk >> 4, gk = (kk & 15) >> 2;
        size_t off = ((size_t)(b * HEADS_ + h) * 32 + (nb >> 5)) * 1024 +
                     dt * 512 + (size_t)((q15v | (gk << 4))) * 8 + half * 4;
        bf16x4 s4 = {f2b(v.x), f2b(v.y), f2b(v.z), f2b(v.w)};
        *(bf16x4*)(vblk + off) = s4;
      }
    }
}

// ---------------------------------------------------------------------------
// offsample4 (round-13 proven)
// ---------------------------------------------------------------------------
__global__ __launch_bounds__(256) void offsample4(
    const float* __restrict__ qd, const short* __restrict__ x2t,
    const float* __restrict__ dwp, const float* __restrict__ dwb,
    const float* __restrict__ lng, const float* __restrict__ lnb,
    const float* __restrict__ offw, short* __restrict__ samp) {
  int bg = blockIdx.x, y = blockIdx.y;
  int tid = threadIdx.x;
  int xg = tid >> 5, cc = tid & 31;
  int x0 = xg << 2, c0 = cc << 2;

  const float* qb = qd + ((size_t)bg * CG_ + c0) * NS_;

  f32x4 dwb4 = *(const f32x4*)(dwb + c0);
  float a[4][4];
#pragma unroll
  for (int i = 0; i < 4; ++i)
#pragma unroll
    for (int p = 0; p < 4; ++p) a[i][p] = dwb4[i];

#pragma unroll
  for (int dy = -2; dy <= 2; ++dy) {
    int yy = y + dy;
    if (yy < 0 || yy > 31) continue;
    f32x4 w0 = *(const f32x4*)(dwp + ((dy + 2) * 5 + 0) * CG_ + c0);
    f32x4 w1 = *(const f32x4*)(dwp + ((dy + 2) * 5 + 1) * CG_ + c0);
    f32x4 w2 = *(const f32x4*)(dwp + ((dy + 2) * 5 + 2) * CG_ + c0);
    f32x4 w3 = *(const f32x4*)(dwp + ((dy + 2) * 5 + 3) * CG_ + c0);
    f32x4 w4 = *(const f32x4*)(dwp + ((dy + 2) * 5 + 4) * CG_ + c0);
#pragma unroll
    for (int i = 0; i < 4; ++i) {
      const float* row = qb + (size_t)i * NS_ + yy * 32;
      f32x4 wa = (f32x4){0.f, 0.f, 0.f, 0.f};
      f32x4 wcv = (f32x4){0.f, 0.f, 0.f, 0.f};
      if (x0 >= 4)  wa  = *(const f32x4*)(row + x0 - 4);
      f32x4 wb = *(const f32x4*)(row + x0);
      if (x0 <= 24) wcv = *(const f32x4*)(row + x0 + 4);
      float w[12] = {wa[0], wa[1], wa[2], wa[3], wb[0], wb[1], wb[2], wb[3],
                     wcv[0], wcv[1], wcv[2], wcv[3]};
      float wt[5] = {w0[i], w1[i], w2[i], w3[i], w4[i]};
#pragma unroll
      for (int p = 0; p < 4; ++p)
#pragma unroll
        for (int j = 0; j < 5; ++j)
          a[i][p] = fmaf(w[p + j + 2], wt[j], a[i][p]);
    }
  }

  f32x4 sum = (f32x4){0.f, 0.f, 0.f, 0.f}, sumsq = sum;
#pragma unroll
  for (int i = 0; i < 4; ++i)
#pragma unroll
    for (int p = 0; p < 4; ++p) { sum[p] += a[i][p]; sumsq[p] += a[i][p] * a[i][p]; }
#pragma unroll
  for (int m = 1; m <= 16; m <<= 1) {
#pragma unroll
    for (int p = 0; p < 4; ++p) {
      sum[p]   += __shfl_xor(sum[p], m);
      sumsq[p] += __shfl_xor(sumsq[p], m);
    }
  }
  f32x4 mu, rs;
#pragma unroll
  for (int p = 0; p < 4; ++p) {
    mu[p] = sum[p] * (1.f / CG_);
    float var = sumsq[p] * (1.f / CG_) - mu[p] * mu[p];
    rs[p] = rsqrtf(var + EPS_);
  }

  f32x4 lg = *(const f32x4*)(lng + c0);
  f32x4 lb = *(const f32x4*)(lnb + c0);
  f32x4 ow0 = *(const f32x4*)(offw + c0);
  f32x4 ow1 = *(const f32x4*)(offw + CG_ + c0);
  f32x4 o0 = (f32x4){0.f, 0.f, 0.f, 0.f}, o1 = o0;
#pragma unroll
  for (int i = 0; i < 4; ++i)
#pragma unroll
    for (int p = 0; p < 4; ++p) {
      float z = (a[i][p] - mu[p]) * rs[p] * lg[i] + lb[i];
      float u = z * fmaf(0.044715f * z, z, 1.f);
      float e = __expf(-1.5957691216057308f * u);
      float ge = z * __builtin_amdgcn_rcpf(1.f + e);
      o0[p] = fmaf(ow0[i], ge, o0[p]);
      o1[p] = fmaf(ow1[i], ge, o1[p]);
    }
#pragma unroll
  for (int m = 1; m <= 16; m <<= 1) {
#pragma unroll
    for (int p = 0; p < 4; ++p) {
      o0[p] += __shfl_xor(o0[p], m);
      o1[p] += __shfl_xor(o1[p], m);
    }
  }

  int b = bg / GROUPS_, gi = bg % GROUPS_;
  const short* xb = x2t + (size_t)bg * NS_ * CG_ + c0;
  float gy = (y + 0.5f) * 0.0625f - 1.f;
#pragma unroll
  for (int p = 0; p < 4; ++p) {
    int x = x0 + p, n = y * 32 + x;
    float gx = (x + 0.5f) * 0.0625f - 1.f;
    float px = fminf(fmaxf(o0[p] + gx, -1.f), 1.f);
    float py = fminf(fmaxf(o1[p] + gy, -1.f), 1.f);
    float ix = (px + 1.f) * 0.5f * 31.f;
    float iy = (py + 1.f) * 0.5f * 31.f;
    float x0f = floorf(ix), y0f = floorf(iy);
    float wx = ix - x0f, wy = iy - y0f;
    int xa = min(max((int)x0f, 0), 31), xbb = min(xa + 1, 31);
    int ya = min(max((int)y0f, 0), 31), yb = min(ya + 1, 31);
    int i00 = ya * 32 + xa, i01 = ya * 32 + xbb;
    int i10 = yb * 32 + xa, i11 = yb * 32 + xbb;
    float w00 = (1.f - wx) * (1.f - wy), w01 = wx * (1.f - wy);
    float w10 = (1.f - wx) * wy,         w11 = wx * wy;
    bf16x4 v00 = *(const bf16x4*)(xb + (size_t)i00 * CG_);
    bf16x4 v01 = *(const bf16x4*)(xb + (size_t)i01 * CG_);
    bf16x4 v10 = *(const bf16x4*)(xb + (size_t)i10 * CG_);
    bf16x4 v11 = *(const bf16x4*)(xb + (size_t)i11 * CG_);
    short out4[4];
#pragma unroll
    for (int j = 0; j < 4; ++j) {
      float v = w00 * b2f(v00[j]) + w01 * b2f(v01[j]) +
                w10 * b2f(v10[j]) + w11 * b2f(v11[j]);
      out4[j] = f2b(v);
    }
    *(bf16x4*)(samp + ((size_t)b * NS_ + n) * C_ + gi * CG_ + c0) = *(bf16x4*)out4;
  }
}

// ---------------------------------------------------------------------------
// Blocked-layout split-K attention (round-13 proven 2-fragment version).
// ---------------------------------------------------------------------------
__global__ __launch_bounds__(256) void attn_split(
    const short* __restrict__ qn, const short* __restrict__ kblk,
    const short* __restrict__ vblk, short* __restrict__ op0,
    short* __restrict__ op1, float* __restrict__ lp) {
  // grid 1536: L = (task%8) + 8*((task/8) + 24*qblk); task = bh*2+s
  int L = blockIdx.x;
  int tq = L >> 3;
  int task = (L & 7) + ((tq % 24) << 3);   // 0..191
  int qblk = tq / 24;                      // 0..7
  int bh = task >> 1, s = task & 1;
  int b = bh / HEADS_, h = bh % HEADS_;
  int wv = threadIdx.x >> 6, lane = threadIdx.x & 63;
  int g = lane >> 4, q15 = lane & 15;
  int q0 = qblk * 128 + wv * 32;

  const short* Qb = qn + (size_t)b * NS_ * C_ + h * HD_;
  const short* Kc = kblk + ((size_t)(b * HEADS_ + h) * 32 + s * 16) * 1024 + lane * 8;
  const short* Vc = vblk + ((size_t)(b * HEADS_ + h) * 32 + s * 16) * 1024 + lane * 8;

  bf16x8 qf[2];
  qf[0] = *(const bf16x8*)(Qb + (size_t)(q0 + q15) * C_ + g * 8);
  qf[1] = *(const bf16x8*)(Qb + (size_t)(q0 + 16 + q15) * C_ + g * 8);

  f32x4 o[2][2];
  o[0][0] = o[0][1] = o[1][0] = o[1][1] = (f32x4){0.f, 0.f, 0.f, 0.f};
  f32x4 lv[2];
  lv[0] = lv[1] = (f32x4){0.f, 0.f, 0.f, 0.f};

#define LOADC(c_, K0, K1, V0, V1)                                              \
  {                                                                            \
    K0 = *(const bf16x8*)(Kc + (c_) * 1024);                                   \
    K1 = *(const bf16x8*)(Kc + (c_) * 1024 + 512);                             \
    V0 = *(const bf16x8*)(Vc + (c_) * 1024);                                   \
    V1 = *(const bf16x8*)(Vc + (c_) * 1024 + 512);                             \
  }

#define COMPUTEC(K0, K1, V0, V1)                                               \
  {                                                                            \
    _Pragma("unroll")                                                          \
    for (int qt = 0; qt < 2; ++qt) {                                           \
      f32x4 z_ = {0.f, 0.f, 0.f, 0.f};                                         \
      f32x4 t0 = MFMA(K0, qf[qt], z_);                                         \
      f32x4 t1 = MFMA(K1, qf[qt], z_);                                         \
      f32x4 e0, e1;                                                            \
      e0.x = EXP2(t0.x); e0.y = EXP2(t0.y); e0.z = EXP2(t0.z); e0.w = EXP2(t0.w);\
      e1.x = EXP2(t1.x); e1.y = EXP2(t1.y); e1.z = EXP2(t1.z); e1.w = EXP2(t1.w);\
      lv[qt] += e0; lv[qt] += e1;                                              \
      union { unsigned u[4]; bf16x8 v; } pu;                                   \
      pu.u[0] = cvtpk(e0.x, e0.y);                                             \
      pu.u[1] = cvtpk(e0.z, e0.w);                                             \
      pu.u[2] = cvtpk(e1.x, e1.y);                                             \
      pu.u[3] = cvtpk(e1.z, e1.w);                                             \
      o[qt][0] = MFMA(V0, pu.v, o[qt][0]);                                     \
      o[qt][1] = MFMA(V1, pu.v, o[qt][1]);                                     \
    }                                                                          \
  }

  bf16x8 kA0, kA1, vA0, vA1, kB0, kB1, vB0, vB1;
  LOADC(0, kA0, kA1, vA0, vA1);
#pragma unroll
  for (int cp = 0; cp < 8; ++cp) {
    LOADC(2 * cp + 1, kB0, kB1, vB0, vB1);
    COMPUTEC(kA0, kA1, vA0, vA1);
    if (cp < 7) LOADC(2 * cp + 2, kA0, kA1, vA0, vA1);
    COMPUTEC(kB0, kB1, vB0, vB1);
  }
#undef LOADC
#undef COMPUTEC

  short* opS = s ? op1 : op0;
#pragma unroll
  for (int qt = 0; qt < 2; ++qt) {
    float lt = (lv[qt].x + lv[qt].y) + (lv[qt].z + lv[qt].w);
    lt += __shfl_xor(lt, 16);
    lt += __shfl_xor(lt, 32);
    int q = q0 + qt * 16 + q15;
    if (g == 0) lp[((size_t)(s * B_ + b) * HEADS_ + h) * NS_ + q] = lt;
#pragma unroll
    for (int dt = 0; dt < 2; ++dt) {
      f32x4 ov = o[qt][dt];
      bf16x4 s4 = {f2b(ov.x), f2b(ov.y), f2b(ov.z), f2b(ov.w)};
      *(bf16x4*)(opS + ((size_t)b * NS_ + q) * C_ + h * HD_ + dt * 16 + g * 4) = s4;
    }
  }
}

// ---------------------------------------------------------------------------
// merge: o = (op0 + op1) / (l0 + l1), out n-major bf16
// ---------------------------------------------------------------------------
__global__ __launch_bounds__(256) void attn_merge(
    const short* __restrict__ op0, const short* __restrict__ op1,
    const float* __restrict__ lp, short* __restrict__ on) {
  int idx = blockIdx.x * 256 + threadIdx.x;
  int c8 = idx % (C_ / 8);
  int q  = (idx / (C_ / 8)) % NS_;
  int b  = idx / ((C_ / 8) * NS_);
  int c0 = c8 * 8, h = c0 >> 5;
  size_t off = ((size_t)b * NS_ + q) * C_ + c0;
  bf16x8 a  = *(const bf16x8*)(op0 + off);
  bf16x8 bb = *(const bf16x8*)(op1 + off);
  float l = lp[((size_t)b * HEADS_ + h) * NS_ + q] +
            lp[((size_t)(B_ + b) * HEADS_ + h) * NS_ + q];
  float rl = 1.f / l;
  short r[8];
#pragma unroll
  for (int j = 0; j < 8; ++j) r[j] = f2b((b2f(a[j]) + b2f(bb[j])) * rl);
  *(bf16x8*)(on + off) = *(bf16x8*)r;
}

// ---------------------------------------------------------------------------
extern "C" void kernel_launch(void* const* d_in, const int* in_sizes, int n_in,
                              void* d_out, int out_size, void* d_ws, size_t ws_size,
                              hipStream_t stream) {
  const float* x1      = (const float*)d_in[0];
  const float* x2      = (const float*)d_in[1];
  const float* Wq      = (const float*)d_in[2];
  const float* bq      = (const float*)d_in[3];
  const float* Wk      = (const float*)d_in[4];
  const float* bk      = (const float*)d_in[5];
  const float* Wv      = (const float*)d_in[6];
  const float* bv      = (const float*)d_in[7];
  const float* Wo      = (const float*)d_in[8];
  const float* bo      = (const float*)d_in[9];
  const float* off_dw  = (const float*)d_in[10];
  const float* off_dwb = (const float*)d_in[11];
  const float* ln_g    = (const float*)d_in[12];
  const float* ln_b    = (const float*)d_in[13];
  const float* off_w   = (const float*)d_in[14];

  char* base = (char*)d_ws;
  const size_t SZ = (size_t)B_ * C_ * NS_;
  float* q_dC  = (float*)base;                   // f32, dead after offsample4
  short* q_nC  = (short*)(base + SZ * 4);
  short* samp  = (short*)(base + SZ * 6);        // dead after gemm_kv
  short* k_blk = (short*)(base + SZ * 8);
  short* v_blk = (short*)(base + SZ * 10);
  short* o_nC  = (short*)(base + SZ * 12);
  short* x1t   = (short*)(base + SZ * 14);       // dead after gemm_nm<1>
  short* x2t   = (short*)(base + SZ * 16);
  short* Wqb   = (short*)(base + SZ * 18);
  short* Wkb   = Wqb + C_ * C_;
  short* Wvb   = Wkb + C_ * C_;
  short* Wob   = Wvb + C_ * C_;
  float* dwp   = (float*)(base + SZ * 18 + (size_t)8 * C_ * C_);
  // attention partials reuse dead regions:
  short* op0   = samp;               // SZ bf16
  short* op1   = x1t;                // SZ bf16
  float* lp    = q_dC;               // 2*B*H*NS f32

  dim3 gg2(NS_ / 64, C_ / 128, B_);   // (16, 3, 8) = 384 blocks

  prep<<<dim3(8461), 256, 0, stream>>>(x1, x2, Wq, Wk, Wv, Wo, off_dw,
                                       x1t, x2t, Wqb, Wkb, Wvb, Wob, dwp);
  gemm_nm<1><<<gg2, 256, 0, stream>>>(x1t, Wqb, bq, nullptr, q_nC, q_dC);
  offsample4<<<dim3(B_ * GROUPS_, 32), 256, 0, stream>>>(
      q_dC, x2t, dwp, off_dwb, ln_g, ln_b, off_w, samp);
  gemm_kv<<<dim3(NS_ / 128, C_ / 64, B_), 256, 0, stream>>>(
      samp, Wkb, Wvb, bk, bv, k_blk, v_blk);
  attn_split<<<dim3(1536), 256, 0, stream>>>(q_nC, k_blk, v_blk, op0, op1, lp);
  attn_merge<<<dim3(B_ * NS_ * (C_ / 8) / 256), 256, 0, stream>>>(op0, op1, lp, o_nC);
  gemm_nm<3><<<gg2, 256, 0, stream>>>(o_nC, Wob, bo, x1, nullptr, (float*)d_out);
}

// Round 18
// 132.181 us; speedup vs baseline: 1.0739x; 1.0465x over previous
//
#include <hip/hip_runtime.h>
#include <math.h>

#define B_  8
#define C_  384
#define NS_ 1024
#define HEADS_ 12
#define HD_ 32
#define GROUPS_ 3
#define CG_ 128
#define EPS_ 1e-5f
// 1/sqrt(32) * log2(e)  (exp computed as exp2)
#define QSC2 (0.17677669529663687f * 1.4426950408889634f)

typedef __attribute__((ext_vector_type(8))) short bf16x8;
typedef __attribute__((ext_vector_type(4))) short bf16x4;
typedef __attribute__((ext_vector_type(4))) float f32x4;
typedef __attribute__((ext_vector_type(8))) __bf16 b8;

static __device__ __forceinline__ short f2b(float f) {
  union { float f; unsigned u; } v; v.f = f;
  unsigned r = v.u + 0x7fffu + ((v.u >> 16) & 1u);   // RNE
  return (short)(r >> 16);
}
static __device__ __forceinline__ float b2f(short s) {
  union { unsigned u; float f; } v; v.u = ((unsigned)(unsigned short)s) << 16;
  return v.f;
}

#if __has_builtin(__builtin_amdgcn_exp2f)
#define EXP2(x) __builtin_amdgcn_exp2f(x)
#else
#define EXP2(x) exp2f(x)
#endif

static __device__ __forceinline__ unsigned cvtpk(float lo, float hi) {
  unsigned r;
  asm("v_cvt_pk_bf16_f32 %0, %1, %2" : "=v"(r) : "v"(lo), "v"(hi));
  return r;
}

static __device__ __forceinline__ f32x4 MFMA(bf16x8 a, bf16x8 b, f32x4 c) {
  return __builtin_amdgcn_mfma_f32_16x16x32_bf16(
      __builtin_bit_cast(b8, a), __builtin_bit_cast(b8, b), c, 0, 0, 0);
}

// ---------------------------------------------------------------------------
// prep mega-kernel (round-13 proven)
// ---------------------------------------------------------------------------
__global__ __launch_bounds__(256) void prep(
    const float* __restrict__ x1, const float* __restrict__ x2,
    const float* __restrict__ Wq, const float* __restrict__ Wk,
    const float* __restrict__ Wv, const float* __restrict__ Wo,
    const float* __restrict__ dw,
    short* __restrict__ x1t, short* __restrict__ x2t,
    short* __restrict__ Wqb, short* __restrict__ Wkb,
    short* __restrict__ Wvb, short* __restrict__ Wob,
    float* __restrict__ dwp) {
  __shared__ float tl[32][33];
  int id = blockIdx.x;
  int tid = threadIdx.x;
  int tx = tid & 31, ty = tid >> 5;
  if (id < 3072) {                       // x1 (8,384,1024) -> (8,1024,384) bf16
    int nb = id & 31, cb = (id >> 5) % 12, b = id / 384;
    int n0 = nb * 32, c0 = cb * 32;
#pragma unroll
    for (int i = 0; i < 4; ++i)
      tl[ty + 8 * i][tx] = x1[((size_t)b * C_ + c0 + ty + 8 * i) * NS_ + n0 + tx];
    __syncthreads();
#pragma unroll
    for (int i = 0; i < 4; ++i)
      x1t[((size_t)b * NS_ + n0 + ty + 8 * i) * C_ + c0 + tx] = f2b(tl[tx][ty + 8 * i]);
  } else if (id < 6144) {                // x2 (24,128,1024) -> (24,1024,128) bf16
    int i = id - 3072;
    int nb = i & 31, cb = (i >> 5) & 3, bg = i / 128;
    int n0 = nb * 32, c0 = cb * 32;
#pragma unroll
    for (int j = 0; j < 4; ++j)
      tl[ty + 8 * j][tx] = x2[((size_t)bg * CG_ + c0 + ty + 8 * j) * NS_ + n0 + tx];
    __syncthreads();
#pragma unroll
    for (int j = 0; j < 4; ++j)
      x2t[((size_t)bg * NS_ + n0 + ty + 8 * j) * CG_ + c0 + tx] = f2b(tl[tx][ty + 8 * j]);
  } else if (id < 8448) {                // weights fp32 -> bf16 (4 x 576 blocks)
    int i = id - 6144;
    int mat = i / 576;
    int e = (i % 576) * 256 + tid;       // < 147456 exactly
    const float* s = mat == 0 ? Wq : mat == 1 ? Wk : mat == 2 ? Wv : Wo;
    short*       d = mat == 0 ? Wqb : mat == 1 ? Wkb : mat == 2 ? Wvb : Wob;
    d[e] = f2b(s[e]);
  } else {                               // dw (128,25) -> dwp (25,128)
    int e = (id - 8448) * 256 + tid;
    if (e < 25 * CG_) { int t = e / CG_, c = e % CG_; dwp[e] = dw[c * 25 + t]; }
  }
}

// ---------------------------------------------------------------------------
// K-loop helpers
// ---------------------------------------------------------------------------
#define GLOADA(kc_, AF)                                                        \
  _Pragma("unroll")                                                            \
  for (int rt = 0; rt < 4; ++rt)                                               \
    AF[rt] = *(const bf16x8*)(Ab + (size_t)(n0 + wr + rt * 16 + r15) * C_ +    \
                              (kc_) + g * 8);
#define GLOADB(kc_, BF, WP, MOFF)                                              \
  _Pragma("unroll")                                                            \
  for (int ct = 0; ct < 4; ++ct)                                               \
    BF[ct] = *(const bf16x8*)((WP) + (size_t)((MOFF) + ct * 16 + r15) * C_ +   \
                              (kc_) + g * 8);
#define GMFMA(AF, BF)                                                          \
  _Pragma("unroll")                                                            \
  for (int rt = 0; rt < 4; ++rt)                                               \
    _Pragma("unroll")                                                          \
    for (int ct = 0; ct < 4; ++ct) acc[rt][ct] = MFMA(AF[rt], BF[ct], acc[rt][ct]);

// ---------------------------------------------------------------------------
// MFMA GEMM (round-13 proven, 128x128 tile, 4 waves, 64x64/wave, acc 4x4).
// MODE 1: outf d-major f32, outb n-major bf16 * QSC2    (q projection)
// MODE 3: outf d-major f32 + res      (final projection + residual)
// ---------------------------------------------------------------------------
template <int MODE>
__global__ __launch_bounds__(256) void gemm_nm(
    const short* __restrict__ A, const short* __restrict__ Wb,
    const float* __restrict__ bias, const float* __restrict__ res,
    short* __restrict__ outb, float* __restrict__ outf) {
  int b = blockIdx.z;
  int n0 = blockIdx.x * 128;
  int m0 = blockIdx.y * 128;
  int wv = threadIdx.x >> 6;
  int lane = threadIdx.x & 63;
  int g = lane >> 4, r15 = lane & 15;
  int wr = (wv >> 1) * 64, wc = (wv & 1) * 64;

  const short* Ab = A + (size_t)b * NS_ * C_;
  f32x4 acc[4][4];
#pragma unroll
  for (int i = 0; i < 4; ++i)
#pragma unroll
    for (int j = 0; j < 4; ++j) acc[i][j] = (f32x4){0.f, 0.f, 0.f, 0.f};

  bf16x8 afA[4], bfA[4], afB[4], bfB[4];
  GLOADA(0, afA); GLOADB(0, bfA, Wb, m0 + wc);
#pragma unroll
  for (int cp = 0; cp < 6; ++cp) {
    GLOADA(64 * cp + 32, afB); GLOADB(64 * cp + 32, bfB, Wb, m0 + wc);
    GMFMA(afA, bfA);
    if (cp < 5) { GLOADA(64 * cp + 64, afA); GLOADB(64 * cp + 64, bfA, Wb, m0 + wc); }
    GMFMA(afB, bfB);
  }

#pragma unroll
  for (int rt = 0; rt < 4; ++rt)
#pragma unroll
    for (int ct = 0; ct < 4; ++ct) {
      int m = m0 + wc + ct * 16 + r15;
      int nb = n0 + wr + rt * 16 + g * 4;
      float bv = bias[m];
      f32x4 v = acc[rt][ct];
      v.x += bv; v.y += bv; v.z += bv; v.w += bv;
      if (MODE == 1) {
        *(f32x4*)(outf + ((size_t)b * C_ + m) * NS_ + nb) = v;
        outb[((size_t)b * NS_ + nb + 0) * C_ + m] = f2b(v.x * QSC2);
        outb[((size_t)b * NS_ + nb + 1) * C_ + m] = f2b(v.y * QSC2);
        outb[((size_t)b * NS_ + nb + 2) * C_ + m] = f2b(v.z * QSC2);
        outb[((size_t)b * NS_ + nb + 3) * C_ + m] = f2b(v.w * QSC2);
      } else {
        const f32x4 rv = *(const f32x4*)(res + ((size_t)b * C_ + m) * NS_ + nb);
        v.x += rv.x; v.y += rv.y; v.z += rv.z; v.w += rv.w;
        *(f32x4*)(outf + ((size_t)b * C_ + m) * NS_ + nb) = v;
      }
    }
}

// ---------------------------------------------------------------------------
// Fused K+V projection GEMM (round-13 proven).
// ---------------------------------------------------------------------------
__global__ __launch_bounds__(256) void gemm_kv(
    const short* __restrict__ A, const short* __restrict__ Wkb,
    const short* __restrict__ Wvb, const float* __restrict__ bkv,
    const float* __restrict__ bvv, short* __restrict__ kblk,
    short* __restrict__ vblk) {
  int b = blockIdx.z;
  int n0 = blockIdx.x * 128;
  int m0 = blockIdx.y * 64;
  int wv = threadIdx.x >> 6;
  int lane = threadIdx.x & 63;
  int g = lane >> 4, r15 = lane & 15;
  int wr = (wv >> 1) * 64;
  int isv = wv & 1;
  const short* Wsel = isv ? Wvb : Wkb;
  const float* bsel = isv ? bvv : bkv;

  const short* Ab = A + (size_t)b * NS_ * C_;
  f32x4 acc[4][4];
#pragma unroll
  for (int i = 0; i < 4; ++i)
#pragma unroll
    for (int j = 0; j < 4; ++j) acc[i][j] = (f32x4){0.f, 0.f, 0.f, 0.f};

  bf16x8 afA[4], bfA[4], afB[4], bfB[4];
  GLOADA(0, afA); GLOADB(0, bfA, Wsel, m0);
#pragma unroll
  for (int cp = 0; cp < 6; ++cp) {
    GLOADA(64 * cp + 32, afB); GLOADB(64 * cp + 32, bfB, Wsel, m0);
    GMFMA(afA, bfA);
    if (cp < 5) { GLOADA(64 * cp + 64, afA); GLOADB(64 * cp + 64, bfA, Wsel, m0); }
    GMFMA(afB, bfB);
  }

#pragma unroll
  for (int rt = 0; rt < 4; ++rt)
#pragma unroll
    for (int ct = 0; ct < 4; ++ct) {
      int m = m0 + ct * 16 + r15;
      int nb = n0 + wr + rt * 16 + g * 4;
      float bv = bsel[m];
      f32x4 v = acc[rt][ct];
      v.x += bv; v.y += bv; v.z += bv; v.w += bv;
      int h = m >> 5, dh = m & 31;
      if (!isv) {
        size_t hb = ((size_t)(b * HEADS_ + h) * 32 + (nb >> 5)) * 1024 +
                    (((nb >> 4) & 1) ? 512 : 0);
        int base_l = (nb & 15) | ((dh >> 3) << 4);
        int jj = dh & 7;
        kblk[hb + (size_t)(base_l + 0) * 8 + jj] = f2b(v.x);
        kblk[hb + (size_t)(base_l + 1) * 8 + jj] = f2b(v.y);
        kblk[hb + (size_t)(base_l + 2) * 8 + jj] = f2b(v.z);
        kblk[hb + (size_t)(base_l + 3) * 8 + jj] = f2b(v.w);
      } else {
        int dt = dh >> 4, q15v = dh & 15;
        int kk = nb & 31;
        int half = kk >> 4, gk = (kk & 15) >> 2;
        size_t off = ((size_t)(b * HEADS_ + h) * 32 + (nb >> 5)) * 1024 +
                     dt * 512 + (size_t)((q15v | (gk << 4))) * 8 + half * 4;
        bf16x4 s4 = {f2b(v.x), f2b(v.y), f2b(v.z), f2b(v.w)};
        *(bf16x4*)(vblk + off) = s4;
      }
    }
}

// ---------------------------------------------------------------------------
// offsample4 (round-13 proven)
// ---------------------------------------------------------------------------
__global__ __launch_bounds__(256) void offsample4(
    const float* __restrict__ qd, const short* __restrict__ x2t,
    const float* __restrict__ dwp, const float* __restrict__ dwb,
    const float* __restrict__ lng, const float* __restrict__ lnb,
    const float* __restrict__ offw, short* __restrict__ samp) {
  int bg = blockIdx.x, y = blockIdx.y;
  int tid = threadIdx.x;
  int xg = tid >> 5, cc = tid & 31;
  int x0 = xg << 2, c0 = cc << 2;

  const float* qb = qd + ((size_t)bg * CG_ + c0) * NS_;

  f32x4 dwb4 = *(const f32x4*)(dwb + c0);
  float a[4][4];
#pragma unroll
  for (int i = 0; i < 4; ++i)
#pragma unroll
    for (int p = 0; p < 4; ++p) a[i][p] = dwb4[i];

#pragma unroll
  for (int dy = -2; dy <= 2; ++dy) {
    int yy = y + dy;
    if (yy < 0 || yy > 31) continue;
    f32x4 w0 = *(const f32x4*)(dwp + ((dy + 2) * 5 + 0) * CG_ + c0);
    f32x4 w1 = *(const f32x4*)(dwp + ((dy + 2) * 5 + 1) * CG_ + c0);
    f32x4 w2 = *(const f32x4*)(dwp + ((dy + 2) * 5 + 2) * CG_ + c0);
    f32x4 w3 = *(const f32x4*)(dwp + ((dy + 2) * 5 + 3) * CG_ + c0);
    f32x4 w4 = *(const f32x4*)(dwp + ((dy + 2) * 5 + 4) * CG_ + c0);
#pragma unroll
    for (int i = 0; i < 4; ++i) {
      const float* row = qb + (size_t)i * NS_ + yy * 32;
      f32x4 wa = (f32x4){0.f, 0.f, 0.f, 0.f};
      f32x4 wcv = (f32x4){0.f, 0.f, 0.f, 0.f};
      if (x0 >= 4)  wa  = *(const f32x4*)(row + x0 - 4);
      f32x4 wb = *(const f32x4*)(row + x0);
      if (x0 <= 24) wcv = *(const f32x4*)(row + x0 + 4);
      float w[12] = {wa[0], wa[1], wa[2], wa[3], wb[0], wb[1], wb[2], wb[3],
                     wcv[0], wcv[1], wcv[2], wcv[3]};
      float wt[5] = {w0[i], w1[i], w2[i], w3[i], w4[i]};
#pragma unroll
      for (int p = 0; p < 4; ++p)
#pragma unroll
        for (int j = 0; j < 5; ++j)
          a[i][p] = fmaf(w[p + j + 2], wt[j], a[i][p]);
    }
  }

  f32x4 sum = (f32x4){0.f, 0.f, 0.f, 0.f}, sumsq = sum;
#pragma unroll
  for (int i = 0; i < 4; ++i)
#pragma unroll
    for (int p = 0; p < 4; ++p) { sum[p] += a[i][p]; sumsq[p] += a[i][p] * a[i][p]; }
#pragma unroll
  for (int m = 1; m <= 16; m <<= 1) {
#pragma unroll
    for (int p = 0; p < 4; ++p) {
      sum[p]   += __shfl_xor(sum[p], m);
      sumsq[p] += __shfl_xor(sumsq[p], m);
    }
  }
  f32x4 mu, rs;
#pragma unroll
  for (int p = 0; p < 4; ++p) {
    mu[p] = sum[p] * (1.f / CG_);
    float var = sumsq[p] * (1.f / CG_) - mu[p] * mu[p];
    rs[p] = rsqrtf(var + EPS_);
  }

  f32x4 lg = *(const f32x4*)(lng + c0);
  f32x4 lb = *(const f32x4*)(lnb + c0);
  f32x4 ow0 = *(const f32x4*)(offw + c0);
  f32x4 ow1 = *(const f32x4*)(offw + CG_ + c0);
  f32x4 o0 = (f32x4){0.f, 0.f, 0.f, 0.f}, o1 = o0;
#pragma unroll
  for (int i = 0; i < 4; ++i)
#pragma unroll
    for (int p = 0; p < 4; ++p) {
      float z = (a[i][p] - mu[p]) * rs[p] * lg[i] + lb[i];
      float u = z * fmaf(0.044715f * z, z, 1.f);
      float e = __expf(-1.5957691216057308f * u);
      float ge = z * __builtin_amdgcn_rcpf(1.f + e);
      o0[p] = fmaf(ow0[i], ge, o0[p]);
      o1[p] = fmaf(ow1[i], ge, o1[p]);
    }
#pragma unroll
  for (int m = 1; m <= 16; m <<= 1) {
#pragma unroll
    for (int p = 0; p < 4; ++p) {
      o0[p] += __shfl_xor(o0[p], m);
      o1[p] += __shfl_xor(o1[p], m);
    }
  }

  int b = bg / GROUPS_, gi = bg % GROUPS_;
  const short* xb = x2t + (size_t)bg * NS_ * CG_ + c0;
  float gy = (y + 0.5f) * 0.0625f - 1.f;
#pragma unroll
  for (int p = 0; p < 4; ++p) {
    int x = x0 + p, n = y * 32 + x;
    float gx = (x + 0.5f) * 0.0625f - 1.f;
    float px = fminf(fmaxf(o0[p] + gx, -1.f), 1.f);
    float py = fminf(fmaxf(o1[p] + gy, -1.f), 1.f);
    float ix = (px + 1.f) * 0.5f * 31.f;
    float iy = (py + 1.f) * 0.5f * 31.f;
    float x0f = floorf(ix), y0f = floorf(iy);
    float wx = ix - x0f, wy = iy - y0f;
    int xa = min(max((int)x0f, 0), 31), xbb = min(xa + 1, 31);
    int ya = min(max((int)y0f, 0), 31), yb = min(ya + 1, 31);
    int i00 = ya * 32 + xa, i01 = ya * 32 + xbb;
    int i10 = yb * 32 + xa, i11 = yb * 32 + xbb;
    float w00 = (1.f - wx) * (1.f - wy), w01 = wx * (1.f - wy);
    float w10 = (1.f - wx) * wy,         w11 = wx * wy;
    bf16x4 v00 = *(const bf16x4*)(xb + (size_t)i00 * CG_);
    bf16x4 v01 = *(const bf16x4*)(xb + (size_t)i01 * CG_);
    bf16x4 v10 = *(const bf16x4*)(xb + (size_t)i10 * CG_);
    bf16x4 v11 = *(const bf16x4*)(xb + (size_t)i11 * CG_);
    short out4[4];
#pragma unroll
    for (int j = 0; j < 4; ++j) {
      float v = w00 * b2f(v00[j]) + w01 * b2f(v01[j]) +
                w10 * b2f(v10[j]) + w11 * b2f(v11[j]);
      out4[j] = f2b(v);
    }
    *(bf16x4*)(samp + ((size_t)b * NS_ + n) * C_ + gi * CG_ + c0) = *(bf16x4*)out4;
  }
}

// ---------------------------------------------------------------------------
// Blocked-layout split-K attention (round-13 proven 2-fragment version):
// 16 chunks/wave, grid 1536, XCD-locality swizzle, 1-deep A/B prefetch.
// ---------------------------------------------------------------------------
__global__ __launch_bounds__(256) void attn_split(
    const short* __restrict__ qn, const short* __restrict__ kblk,
    const short* __restrict__ vblk, short* __restrict__ op0,
    short* __restrict__ op1, float* __restrict__ lp) {
  // grid 1536: L = (task%8) + 8*((task/8) + 24*qblk); task = bh*2+s
  int L = blockIdx.x;
  int tq = L >> 3;
  int task = (L & 7) + ((tq % 24) << 3);   // 0..191
  int qblk = tq / 24;                      // 0..7
  int bh = task >> 1, s = task & 1;
  int b = bh / HEADS_, h = bh % HEADS_;
  int wv = threadIdx.x >> 6, lane = threadIdx.x & 63;
  int g = lane >> 4, q15 = lane & 15;
  int q0 = qblk * 128 + wv * 32;

  const short* Qb = qn + (size_t)b * NS_ * C_ + h * HD_;
  const short* Kc = kblk + ((size_t)(b * HEADS_ + h) * 32 + s * 16) * 1024 + lane * 8;
  const short* Vc = vblk + ((size_t)(b * HEADS_ + h) * 32 + s * 16) * 1024 + lane * 8;

  bf16x8 qf[2];
  qf[0] = *(const bf16x8*)(Qb + (size_t)(q0 + q15) * C_ + g * 8);
  qf[1] = *(const bf16x8*)(Qb + (size_t)(q0 + 16 + q15) * C_ + g * 8);

  f32x4 o[2][2];
  o[0][0] = o[0][1] = o[1][0] = o[1][1] = (f32x4){0.f, 0.f, 0.f, 0.f};
  f32x4 lv[2];
  lv[0] = lv[1] = (f32x4){0.f, 0.f, 0.f, 0.f};

#define LOADC(c_, K0, K1, V0, V1)                                              \
  {                                                                            \
    K0 = *(const bf16x8*)(Kc + (c_) * 1024);                                   \
    K1 = *(const bf16x8*)(Kc + (c_) * 1024 + 512);                             \
    V0 = *(const bf16x8*)(Vc + (c_) * 1024);                                   \
    V1 = *(const bf16x8*)(Vc + (c_) * 1024 + 512);                             \
  }

#define COMPUTEC(K0, K1, V0, V1)                                               \
  {                                                                            \
    _Pragma("unroll")                                                          \
    for (int qt = 0; qt < 2; ++qt) {                                           \
      f32x4 z_ = {0.f, 0.f, 0.f, 0.f};                                         \
      f32x4 t0 = MFMA(K0, qf[qt], z_);                                         \
      f32x4 t1 = MFMA(K1, qf[qt], z_);                                         \
      f32x4 e0, e1;                                                            \
      e0.x = EXP2(t0.x); e0.y = EXP2(t0.y); e0.z = EXP2(t0.z); e0.w = EXP2(t0.w);\
      e1.x = EXP2(t1.x); e1.y = EXP2(t1.y); e1.z = EXP2(t1.z); e1.w = EXP2(t1.w);\
      lv[qt] += e0; lv[qt] += e1;                                              \
      union { unsigned u[4]; bf16x8 v; } pu;                                   \
      pu.u[0] = cvtpk(e0.x, e0.y);                                             \
      pu.u[1] = cvtpk(e0.z, e0.w);                                             \
      pu.u[2] = cvtpk(e1.x, e1.y);                                             \
      pu.u[3] = cvtpk(e1.z, e1.w);                                             \
      o[qt][0] = MFMA(V0, pu.v, o[qt][0]);                                     \
      o[qt][1] = MFMA(V1, pu.v, o[qt][1]);                                     \
    }                                                                          \
  }

  bf16x8 kA0, kA1, vA0, vA1, kB0, kB1, vB0, vB1;
  LOADC(0, kA0, kA1, vA0, vA1);
#pragma unroll
  for (int cp = 0; cp < 8; ++cp) {
    LOADC(2 * cp + 1, kB0, kB1, vB0, vB1);
    COMPUTEC(kA0, kA1, vA0, vA1);
    if (cp < 7) LOADC(2 * cp + 2, kA0, kA1, vA0, vA1);
    COMPUTEC(kB0, kB1, vB0, vB1);
  }
#undef LOADC
#undef COMPUTEC

  short* opS = s ? op1 : op0;
#pragma unroll
  for (int qt = 0; qt < 2; ++qt) {
    float lt = (lv[qt].x + lv[qt].y) + (lv[qt].z + lv[qt].w);
    lt += __shfl_xor(lt, 16);
    lt += __shfl_xor(lt, 32);
    int q = q0 + qt * 16 + q15;
    if (g == 0) lp[((size_t)(s * B_ + b) * HEADS_ + h) * NS_ + q] = lt;
#pragma unroll
    for (int dt = 0; dt < 2; ++dt) {
      f32x4 ov = o[qt][dt];
      bf16x4 s4 = {f2b(ov.x), f2b(ov.y), f2b(ov.z), f2b(ov.w)};
      *(bf16x4*)(opS + ((size_t)b * NS_ + q) * C_ + h * HD_ + dt * 16 + g * 4) = s4;
    }
  }
}

// ---------------------------------------------------------------------------
// merge: o = (op0 + op1) / (l0 + l1), out n-major bf16
// ---------------------------------------------------------------------------
__global__ __launch_bounds__(256) void attn_merge(
    const short* __restrict__ op0, const short* __restrict__ op1,
    const float* __restrict__ lp, short* __restrict__ on) {
  int idx = blockIdx.x * 256 + threadIdx.x;
  int c8 = idx % (C_ / 8);
  int q  = (idx / (C_ / 8)) % NS_;
  int b  = idx / ((C_ / 8) * NS_);
  int c0 = c8 * 8, h = c0 >> 5;
  size_t off = ((size_t)b * NS_ + q) * C_ + c0;
  bf16x8 a  = *(const bf16x8*)(op0 + off);
  bf16x8 bb = *(const bf16x8*)(op1 + off);
  float l = lp[((size_t)b * HEADS_ + h) * NS_ + q] +
            lp[((size_t)(B_ + b) * HEADS_ + h) * NS_ + q];
  float rl = 1.f / l;
  short r[8];
#pragma unroll
  for (int j = 0; j < 8; ++j) r[j] = f2b((b2f(a[j]) + b2f(bb[j])) * rl);
  *(bf16x8*)(on + off) = *(bf16x8*)r;
}

// ---------------------------------------------------------------------------
extern "C" void kernel_launch(void* const* d_in, const int* in_sizes, int n_in,
                              void* d_out, int out_size, void* d_ws, size_t ws_size,
                              hipStream_t stream) {
  const float* x1      = (const float*)d_in[0];
  const float* x2      = (const float*)d_in[1];
  const float* Wq      = (const float*)d_in[2];
  const float* bq      = (const float*)d_in[3];
  const float* Wk      = (const float*)d_in[4];
  const float* bk      = (const float*)d_in[5];
  const float* Wv      = (const float*)d_in[6];
  const float* bv      = (const float*)d_in[7];
  const float* Wo      = (const float*)d_in[8];
  const float* bo      = (const float*)d_in[9];
  const float* off_dw  = (const float*)d_in[10];
  const float* off_dwb = (const float*)d_in[11];
  const float* ln_g    = (const float*)d_in[12];
  const float* ln_b    = (const float*)d_in[13];
  const float* off_w   = (const float*)d_in[14];

  char* base = (char*)d_ws;
  const size_t SZ = (size_t)B_ * C_ * NS_;
  float* q_dC  = (float*)base;                   // f32, dead after offsample4
  short* q_nC  = (short*)(base + SZ * 4);
  short* samp  = (short*)(base + SZ * 6);        // dead after gemm_kv
  short* k_blk = (short*)(base + SZ * 8);
  short* v_blk = (short*)(base + SZ * 10);
  short* o_nC  = (short*)(base + SZ * 12);
  short* x1t   = (short*)(base + SZ * 14);       // dead after gemm_nm<1>
  short* x2t   = (short*)(base + SZ * 16);
  short* Wqb   = (short*)(base + SZ * 18);
  short* Wkb   = Wqb + C_ * C_;
  short* Wvb   = Wkb + C_ * C_;
  short* Wob   = Wvb + C_ * C_;
  float* dwp   = (float*)(base + SZ * 18 + (size_t)8 * C_ * C_);
  // attention partials reuse dead regions:
  short* op0   = samp;               // SZ bf16
  short* op1   = x1t;                // SZ bf16
  float* lp    = q_dC;               // 2*B*H*NS f32

  dim3 gg(NS_ / 128, C_ / 128, B_);   // (8, 3, 8)

  prep<<<dim3(8461), 256, 0, stream>>>(x1, x2, Wq, Wk, Wv, Wo, off_dw,
                                       x1t, x2t, Wqb, Wkb, Wvb, Wob, dwp);
  gemm_nm<1><<<gg, 256, 0, stream>>>(x1t, Wqb, bq, nullptr, q_nC, q_dC);
  offsample4<<<dim3(B_ * GROUPS_, 32), 256, 0, stream>>>(
      q_dC, x2t, dwp, off_dwb, ln_g, ln_b, off_w, samp);
  gemm_kv<<<dim3(NS_ / 128, C_ / 64, B_), 256, 0, stream>>>(
      samp, Wkb, Wvb, bk, bv, k_blk, v_blk);
  attn_split<<<dim3(1536), 256, 0, stream>>>(q_nC, k_blk, v_blk, op0, op1, lp);
  attn_merge<<<dim3(B_ * NS_ * (C_ / 8) / 256), 256, 0, stream>>>(op0, op1, lp, o_nC);
  gemm_nm<3><<<gg, 256, 0, stream>>>(o_nC, Wob, bo, x1, nullptr, (float*)d_out);
}